// Round 7
// baseline (406.748 us; speedup 1.0000x reference)
//
#include <hip/hip_runtime.h>
#include <hip/hip_bf16.h>

// ---------------------------------------------------------------------------
// Transformer block forward (B=4, T=2048, C=1024, F=4096).
// GEMM engine: 256x256 tile, BK=64, 512 threads (8 waves 2Mx4N, 128x64 per
// wave, acc[8][4]).  4 phases per K-tile:
//   ph0: {8 ds_read kk0 | stage kk0' A+B (4 gload_lds) | bar | 16 MFMA | bar}
//   ph1: {4 ds_read     | vmcnt(4) bar                 | 16 MFMA | bar}
//   ph2: {8 ds_read kk1 | stage kk1' A+B               | bar | 16 MFMA | bar}
//   ph3: {4 ds_read     | vmcnt(4) bar                 | 16 MFMA | bar}
// Drained loads are always 3 phases old; never vmcnt(0) mid-loop.  No manual
// lgkmcnt(0): compiler emits progressive lgkmcnt before each MFMA use, so
// MFMA starts while trailing ds_reads land.  sched_barrier(0) pins the MFMA
// cluster between barriers.  T2 (row>>2)&3 swizzle, T5 setprio, T1 XCD swz.
// ---------------------------------------------------------------------------

typedef __bf16 bf16x8_t __attribute__((ext_vector_type(8)));
typedef float f32x4_t __attribute__((ext_vector_type(4)));

__device__ __forceinline__ unsigned short f2bf(float f) {
    unsigned int u = __float_as_uint(f);
    u += 0x7fffu + ((u >> 16) & 1u);   // round-to-nearest-even
    return (unsigned short)(u >> 16);
}
__device__ __forceinline__ float bf2f(unsigned short u) {
    return __uint_as_float((unsigned int)u << 16);
}

__device__ __forceinline__ void gload16(const void* g, void* lds) {
    __builtin_amdgcn_global_load_lds(
        (const __attribute__((address_space(1))) unsigned int*)g,
        (__attribute__((address_space(3))) unsigned int*)lds, 16, 0, 0);
}

#define SB0() __builtin_amdgcn_sched_barrier(0)
#define BAR() asm volatile("s_barrier" ::: "memory")
#define VM4_BAR() asm volatile("s_waitcnt vmcnt(4)\ns_barrier" ::: "memory")
#define VM0_BAR() asm volatile("s_waitcnt vmcnt(0)\ns_barrier" ::: "memory")

enum { EPI_F32 = 0, EPI_BF16 = 1, EPI_BIAS_RELU_BF16 = 2, EPI_RESID_F32 = 3,
       EPI_BIAS_RESID_F32 = 4 };

// C = A @ B^T (+epilogue).  A: [M][lda] bf16 row-major, B: [N][ldb] bf16.
// CSKIP: skip tiles above causal diagonal.  KLIM: Keff = row0+256.
// LDS (bytes): buf*65536 + kk*32768 + op*16384 (op:0=A,1=B); region = 256
// rows x 32 k bf16; 16B chunk c=row*4+s at byte c*16; LDS(row,s) holds global
// k-slot s ^ ((row>>2)&3); reads XOR the same.
template <int EPI, bool CSKIP, bool KLIM>
__global__ __launch_bounds__(512, 2) void gemm256(
    const unsigned short* __restrict__ A,
    const unsigned short* __restrict__ Bm,
    void* __restrict__ Cout,
    const float* __restrict__ bias,
    const float* __restrict__ resid,
    int M, int N, int K, int lda, int ldb, float scale,
    long long batA, long long batB, long long batC, long long batR)
{
    __shared__ __align__(16) unsigned char lds[131072];

    // T1: bijective XCD swizzle of flattened block id (all grids: nwg%8==0)
    const int gx = gridDim.x;
    const int nwg = gx * gridDim.y;
    int bl = blockIdx.y * gx + blockIdx.x;
    bl = (bl & 7) * (nwg >> 3) + (bl >> 3);
    const int bx = bl % gx, by = bl / gx;

    const int row0 = by * 256, col0 = bx * 256;
    if (CSKIP && col0 > row0) return;

    const int bz = blockIdx.z;
    const unsigned short* Ab = A + (long long)bz * batA + (long long)row0 * lda;
    const unsigned short* Bb = Bm + (long long)bz * batB + (long long)col0 * ldb;

    const int tid = threadIdx.x, lane = tid & 63, wid = tid >> 6;
    const int wrM = (wid >> 2) * 128;     // wave row origin (2 x 128)
    const int wcN = (wid & 3) * 64;       // wave col origin (4 x 64)
    const int lr = lane & 15, lg = lane >> 4;

    int Keff = K;
    if (KLIM) { int kl = row0 + 256; Keff = kl < K ? kl : K; }
    const int nkt = Keff >> 6;            // K-tiles of 64 (all calls: nkt>=4)

    // ---- staging: wave covers chunks [wid*128, wid*128+128), 2 per thread
    const int c0 = wid * 128 + lane;
    const int crow = c0 >> 2;                          // +16 for second chunk
    const int sg = (c0 & 3) ^ ((c0 >> 4) & 3);          // T2 source slot
    const unsigned short* gA0 = Ab + (long long)crow * lda + sg * 8;
    const unsigned short* gA1 = gA0 + 16ll * lda;
    const unsigned short* gB0 = Bb + (long long)crow * ldb + sg * 8;
    const unsigned short* gB1 = gB0 + 16ll * ldb;

    // ---- fragment read offsets (bytes within region) ----
    const int sw = (lg ^ ((lr >> 2) & 3)) << 4;        // T2 read swizzle
    const int aoff = (wrM + lr) * 64 + sw;             // + m*1024
    const int boff = 16384 + (wcN + lr) * 64 + sw;     // + n*1024

    f32x4_t acc[8][4];
#pragma unroll
    for (int m = 0; m < 8; ++m)
#pragma unroll
        for (int n = 0; n < 4; ++n)
            acc[m][n] = (f32x4_t){0.f, 0.f, 0.f, 0.f};

    // stage region r (0=A-kk0,1=B-kk0,2=A-kk1,3=B-kk1) of tile ktn into buf b
    auto stageR = [&](int b, int r, int ktn) {
        const int kk = r >> 1, op = r & 1;
        const int ke = ktn * 64 + kk * 32;
        unsigned char* d = lds + b * 65536 + kk * 32768 + op * 16384 + wid * 2048;
        const unsigned short* g0 = (op ? gB0 : gA0) + ke;
        const unsigned short* g1 = (op ? gB1 : gA1) + ke;
        gload16(g0, d);
        gload16(g1, d + 1024);
    };

    bf16x8_t af[4], bv[4];
    auto dsA4 = [&](int b, int kk, int mq) {
        const unsigned char* u = lds + b * 65536 + kk * 32768;
#pragma unroll
        for (int j = 0; j < 4; ++j)
            af[j] = *(const bf16x8_t*)(u + aoff + (mq * 4 + j) * 1024);
    };
    auto dsB4 = [&](int b, int kk) {
        const unsigned char* u = lds + b * 65536 + kk * 32768;
#pragma unroll
        for (int n = 0; n < 4; ++n)
            bv[n] = *(const bf16x8_t*)(u + boff + n * 1024);
    };
    auto mf16 = [&](int mq) {
        __builtin_amdgcn_s_setprio(1);
#pragma unroll
        for (int j = 0; j < 4; ++j)
#pragma unroll
            for (int n = 0; n < 4; ++n)
                acc[mq * 4 + j][n] = __builtin_amdgcn_mfma_f32_16x16x32_bf16(
                    af[j], bv[n], acc[mq * 4 + j][n], 0, 0, 0);
        __builtin_amdgcn_s_setprio(0);
    };

    // prologue: stage tile0 fully (A0,B0,A1,B1 = 8 gloads); drain kk0's 4.
    stageR(0, 0, 0); stageR(0, 1, 0); stageR(0, 2, 0); stageR(0, 3, 0);
    VM4_BAR();

    // Ledger (per-thread, entering ph0 of tile t): outstanding = kk1(t) [4,
    // issued ph2(t-1)].  ph0:+4 (kk0(t+1)) ->8.  ph1: vmcnt(4) drains kk1(t)
    // (3 phases old; read at ph2).  ph2:+4 (kk1(t+1)) ->8.  ph3: vmcnt(4)
    // drains kk0(t+1) (3 phases old; read at ph0(t+1)).
    int kt = 0;
    for (; kt < nkt - 1; ++kt) {
        const int buf = kt & 1, nb = buf ^ 1;
        // ph0: kk0, m-quad 0
        dsA4(buf, 0, 0); dsB4(buf, 0);
        stageR(nb, 0, kt + 1); stageR(nb, 1, kt + 1);
        BAR(); SB0();
        mf16(0); SB0();
        BAR();
        // ph1: kk0, m-quad 1 (B reused in regs)
        dsA4(buf, 0, 1);
        VM4_BAR(); SB0();
        mf16(1); SB0();
        BAR();
        // ph2: kk1, m-quad 0
        dsA4(buf, 1, 0); dsB4(buf, 1);
        stageR(nb, 2, kt + 1); stageR(nb, 3, kt + 1);
        BAR(); SB0();
        mf16(0); SB0();
        BAR();
        // ph3: kk1, m-quad 1
        dsA4(buf, 1, 1);
        VM4_BAR(); SB0();
        mf16(1); SB0();
        BAR();
    }
    {   // tail tile: no staging; kk1(last) drained at ph1 (3 phases old)
        const int buf = kt & 1;
        dsA4(buf, 0, 0); dsB4(buf, 0);
        BAR(); SB0();
        mf16(0); SB0();
        BAR();
        dsA4(buf, 0, 1);
        VM0_BAR(); SB0();
        mf16(1); SB0();
        BAR();
        dsA4(buf, 1, 0); dsB4(buf, 1);
        BAR(); SB0();
        mf16(0); SB0();
        BAR();
        dsA4(buf, 1, 1);
        SB0();
        mf16(1); SB0();
    }

    // ---- epilogue ----
    const int ldc = N;
    float* Cf = (float*)Cout + (long long)bz * batC;
    unsigned short* Cb = (unsigned short*)Cout + (long long)bz * batC;
    const float* R = nullptr;
    if constexpr (EPI == EPI_RESID_F32 || EPI == EPI_BIAS_RESID_F32)
        R = resid + (long long)bz * batR;

#pragma unroll
    for (int m = 0; m < 8; ++m)
#pragma unroll
        for (int n = 0; n < 4; ++n)
#pragma unroll
            for (int j = 0; j < 4; ++j) {
                const int row = row0 + wrM + m * 16 + lg * 4 + j;
                const int col = col0 + wcN + n * 16 + lr;
                const long long idx = (long long)row * ldc + col;
                float v = acc[m][n][j] * scale;
                if constexpr (EPI == EPI_F32) {
                    Cf[idx] = v;
                } else if constexpr (EPI == EPI_BF16) {
                    Cb[idx] = f2bf(v);
                } else if constexpr (EPI == EPI_BIAS_RELU_BF16) {
                    v += bias[col];
                    v = v > 0.f ? v : 0.f;
                    Cb[idx] = f2bf(v);
                } else if constexpr (EPI == EPI_RESID_F32) {
                    Cf[idx] = v + R[idx];
                } else {  // EPI_BIAS_RESID_F32
                    Cf[idx] = v + bias[col] + R[idx];
                }
            }
}

// ------------- transpose + fp32->bf16 convert: in [R][Cc] -> out [Cc][R] ----
__global__ __launch_bounds__(256) void tconv_k(
    const float* __restrict__ in, unsigned short* __restrict__ out,
    int R, int Cc)
{
    __shared__ float t[64][65];
    const int r0 = blockIdx.y * 64, c0 = blockIdx.x * 64;
    const int tid = threadIdx.x;
    const int a = tid >> 4;
    const int b = tid & 15;
#pragma unroll
    for (int i = 0; i < 4; ++i) {
        const int row = a + i * 16;
        float4 v = *(const float4*)(in + (long long)(r0 + row) * Cc + c0 + b * 4);
        t[row][b * 4 + 0] = v.x; t[row][b * 4 + 1] = v.y;
        t[row][b * 4 + 2] = v.z; t[row][b * 4 + 3] = v.w;
    }
    __syncthreads();
#pragma unroll
    for (int i = 0; i < 4; ++i) {
        const int oc = a + i * 16;
        ushort4 o;
        o.x = f2bf(t[b * 4 + 0][oc]);
        o.y = f2bf(t[b * 4 + 1][oc]);
        o.z = f2bf(t[b * 4 + 2][oc]);
        o.w = f2bf(t[b * 4 + 3][oc]);
        *(ushort4*)(out + (long long)(c0 + oc) * R + r0 + b * 4) = o;
    }
}

// ------ bf16 transpose of the v-slice: qkv[8192][3072]@col2048 -> vT[1024][8192]
__global__ __launch_bounds__(256) void vtrans_k(
    const unsigned short* __restrict__ in, unsigned short* __restrict__ out)
{
    __shared__ unsigned short t[64][72];
    const int r0 = blockIdx.x * 64;       // rows of in (time)
    const int c0 = blockIdx.y * 64;       // cols of v (channel)
    const int tid = threadIdx.x;
#pragma unroll
    for (int i = 0; i < 2; ++i) {
        const int ch = tid * 2 + i;       // 0..511
        const int row = ch >> 3, cs = ch & 7;
        int4 v = *(const int4*)(in + (long long)(r0 + row) * 3072 + 2048 + c0 + cs * 8);
        *(int4*)&t[row][cs * 8] = v;      // 144B rows -> 16B-aligned slots
    }
    __syncthreads();
#pragma unroll
    for (int i = 0; i < 2; ++i) {
        const int w = tid * 2 + i;
        const int oc = w >> 3, orc = w & 7;
        unsigned short tmp[8];
#pragma unroll
        for (int j = 0; j < 8; ++j) tmp[j] = t[orc * 8 + j][oc];
        *(int4*)(out + (long long)(c0 + oc) * 8192 + r0 + orc * 8) = *(const int4*)tmp;
    }
}

// ---------------- LayerNorm: one wave per 1024-elem row ---------------------
__global__ __launch_bounds__(256) void ln_k(
    const float* __restrict__ x, const float* __restrict__ g,
    const float* __restrict__ be, unsigned short* __restrict__ out)
{
    const int wv = threadIdx.x >> 6, lane = threadIdx.x & 63;
    const long long row = blockIdx.x * 4 + wv;
    const float* xr = x + row * 1024;
    float4 v[4];
    float s = 0.f, q = 0.f;
#pragma unroll
    for (int j = 0; j < 4; ++j) {
        v[j] = *(const float4*)(xr + j * 256 + lane * 4);
        s += v[j].x + v[j].y + v[j].z + v[j].w;
        q += v[j].x * v[j].x + v[j].y * v[j].y + v[j].z * v[j].z + v[j].w * v[j].w;
    }
#pragma unroll
    for (int off = 32; off > 0; off >>= 1) {
        s += __shfl_xor(s, off);
        q += __shfl_xor(q, off);
    }
    const float mean = s * (1.0f / 1024.0f);
    const float var  = q * (1.0f / 1024.0f) - mean * mean;
    const float rstd = rsqrtf(var + 1e-5f);
#pragma unroll
    for (int j = 0; j < 4; ++j) {
        float4 gv = *(const float4*)(g + j * 256 + lane * 4);
        float4 bv = *(const float4*)(be + j * 256 + lane * 4);
        ushort4 o;
        o.x = f2bf((v[j].x - mean) * rstd * gv.x + bv.x);
        o.y = f2bf((v[j].y - mean) * rstd * gv.y + bv.y);
        o.z = f2bf((v[j].z - mean) * rstd * gv.z + bv.z);
        o.w = f2bf((v[j].w - mean) * rstd * gv.w + bv.w);
        *(ushort4*)(out + row * 1024 + j * 256 + lane * 4) = o;
    }
}

// ------------- causal row softmax: S bf16 -> P bf16 (zero-padded) ----------
__global__ __launch_bounds__(256) void softmax_k(
    const unsigned short* __restrict__ S, unsigned short* __restrict__ P, int T)
{
    __shared__ float rowl[2048];
    __shared__ float sred[4];
    const int t = blockIdx.x;
    const long long base = ((long long)blockIdx.y * T + t) * (long long)T;
    const unsigned short* srow = S + base;
    unsigned short* prow = P + base;
    const int n = t + 1;                       // valid causal length
    const int lim = ((t >> 8) + 1) << 8;       // zero-fill to 256 boundary
    const int tid = threadIdx.x;

    const int n8 = n >> 3;
    for (int i = tid; i < n8; i += 256) {
        int4 r = ((const int4*)srow)[i];
        const unsigned short* u = (const unsigned short*)&r;
#pragma unroll
        for (int j = 0; j < 8; ++j) rowl[i * 8 + j] = bf2f(u[j]);
    }
    for (int i = (n8 << 3) + tid; i < n; i += 256) rowl[i] = bf2f(srow[i]);
    __syncthreads();

    float mx = -3.0e38f;
    for (int i = tid; i < n; i += 256) mx = fmaxf(mx, rowl[i]);
#pragma unroll
    for (int off = 32; off > 0; off >>= 1) mx = fmaxf(mx, __shfl_xor(mx, off));
    if ((tid & 63) == 0) sred[tid >> 6] = mx;
    __syncthreads();
    mx = fmaxf(fmaxf(sred[0], sred[1]), fmaxf(sred[2], sred[3]));
    __syncthreads();

    float sum = 0.f;
    for (int i = tid; i < n; i += 256) {
        float e = __expf(rowl[i] - mx);
        rowl[i] = e;
        sum += e;
    }
#pragma unroll
    for (int off = 32; off > 0; off >>= 1) sum += __shfl_xor(sum, off);
    if ((tid & 63) == 0) sred[tid >> 6] = sum;
    __syncthreads();
    sum = sred[0] + sred[1] + sred[2] + sred[3];
    const float inv = 1.0f / sum;

    for (int i = tid; i < n; i += 256) prow[i] = f2bf(rowl[i] * inv);
    for (int i = n + tid; i < lim; i += 256) prow[i] = 0;
}

// -------- ff2 finalize: out = p0 + p1 + bias[col] + xres (all fp32) --------
__global__ __launch_bounds__(256) void ffadd_k(
    const float4* __restrict__ p0, const float4* __restrict__ p1,
    const float4* __restrict__ xr, const float4* __restrict__ b2,
    float4* __restrict__ out, int n4)
{
    int i = blockIdx.x * 256 + threadIdx.x;
    const int stride = gridDim.x * 256;
    for (; i < n4; i += stride) {
        float4 a = p0[i], b = p1[i], c = xr[i], d = b2[i & 255];
        float4 o;
        o.x = a.x + b.x + c.x + d.x;
        o.y = a.y + b.y + c.y + d.y;
        o.z = a.z + b.z + c.z + d.z;
        o.w = a.w + b.w + c.w + d.w;
        out[i] = o;
    }
}

// ---------------------------------------------------------------------------
extern "C" void kernel_launch(void* const* d_in, const int* in_sizes, int n_in,
                              void* d_out, int out_size, void* d_ws, size_t ws_size,
                              hipStream_t stream)
{
    const int B = 4, T = 2048, C = 1024, F = 4096;
    const float* x   = (const float*)d_in[0];
    const float* Wk  = (const float*)d_in[1];
    const float* Wq  = (const float*)d_in[2];
    const float* Wv  = (const float*)d_in[3];
    const float* W1  = (const float*)d_in[4];
    const float* b1  = (const float*)d_in[5];
    const float* W2  = (const float*)d_in[6];
    const float* b2  = (const float*)d_in[7];
    const float* g1  = (const float*)d_in[8];
    const float* be1 = (const float*)d_in[9];
    const float* g2  = (const float*)d_in[10];
    const float* be2 = (const float*)d_in[11];

    char* ws = (char*)d_ws;
    const size_t MB = 1ull << 20;
    unsigned short* h     = (unsigned short*)(ws + 0);         // 16 MiB
    unsigned short* qkv   = (unsigned short*)(ws + 16 * MB);   // 48 MiB [8192][3072]
    unsigned short* vT    = (unsigned short*)(ws + 64 * MB);   // 16 MiB [1024][8192]
    float*          pbuf  = (float*)(ws + 16 * MB);            // 64 MiB (aliases qkv+vT; used after pv)
    float*          xres  = (float*)(ws + 80 * MB);            // 32 MiB
    unsigned short* S     = (unsigned short*)(ws + 112 * MB);  // 32 MiB bf16 [B][T][T]
    unsigned short* P     = (unsigned short*)(ws + 144 * MB);  // 32 MiB
    unsigned short* ff1   = (unsigned short*)(ws + 112 * MB);  // 64 MiB (aliases S+P; used after pv)
    unsigned short* wqkvT = (unsigned short*)(ws + 176 * MB);  // 6 MiB [3C][C]
    unsigned short* w1T   = (unsigned short*)(ws + 182 * MB);  // 8 MiB [F][C]
    unsigned short* w2T   = (unsigned short*)(ws + 190 * MB);  // 8 MiB [C][F]  (end 198 MiB)

    // transposed weight converts (q,k,v fused into wqkvT)
    tconv_k<<<dim3(16, 16), 256, 0, stream>>>(Wq, wqkvT, C, C);
    tconv_k<<<dim3(16, 16), 256, 0, stream>>>(Wk, wqkvT + C * C, C, C);
    tconv_k<<<dim3(16, 16), 256, 0, stream>>>(Wv, wqkvT + 2 * C * C, C, C);
    tconv_k<<<dim3(64, 16), 256, 0, stream>>>(W1, w1T, C, F);
    tconv_k<<<dim3(16, 64), 256, 0, stream>>>(W2, w2T, F, C);

    // LN1
    ln_k<<<dim3(B * T / 4), 256, 0, stream>>>(x, g1, be1, h);

    // [q|k|v] = h @ [Wq|Wk|Wv]   (M=8192, N=3072, K=1024) -> 384 blocks
    dim3 gqkv(3 * C / 256, (B * T) / 256, 1);
    gemm256<EPI_BF16, false, false><<<gqkv, 512, 0, stream>>>(
        h, wqkvT, qkv, nullptr, nullptr, B * T, 3 * C, C, C, C, 1.0f, 0, 0, 0, 0);

    // vT = transpose of v-slice
    vtrans_k<<<dim3(B * T / 64, C / 64), 256, 0, stream>>>(qkv, vT);

    // S = q @ k^T / 32 (bf16 out; causal tiles only) -> 144 alive
    dim3 gsc(T / 256, T / 256, B);
    gemm256<EPI_BF16, true, false><<<gsc, 512, 0, stream>>>(
        qkv, qkv + C, S, nullptr, nullptr, T, T, C, 3 * C, 3 * C, 0.03125f,
        (long long)T * 3 * C, (long long)T * 3 * C, (long long)T * T, 0);

    // P = causal softmax(S)
    softmax_k<<<dim3(T, B), 256, 0, stream>>>(S, P, T);

    // xres = x + P @ v  (B = vT [C][8192], batch col-offset T) -> 128 blocks
    dim3 gsa(C / 256, T / 256, B);
    gemm256<EPI_RESID_F32, false, true><<<gsa, 512, 0, stream>>>(
        P, vT, xres, nullptr, x, T, C, T, T, B * T, 1.0f,
        (long long)T * T, (long long)T, (long long)T * C, (long long)T * C);

    // LN2
    ln_k<<<dim3(B * T / 4), 256, 0, stream>>>(xres, g2, be2, h);

    // ff1 = relu(h @ W1 + b1)   (M=8192, N=4096, K=1024) -> 512 blocks
    dim3 gf1(F / 256, (B * T) / 256, 1);
    gemm256<EPI_BIAS_RELU_BF16, false, false><<<gf1, 512, 0, stream>>>(
        h, w1T, ff1, b1, nullptr, B * T, F, C, C, C, 1.0f, 0, 0, 0, 0);

    // ff2 split-K z=2: partials = ff1[:, z*2048:] @ W2[z*2048:, :] -> 256 blocks
    dim3 gf2(C / 256, (B * T) / 256, 2);
    gemm256<EPI_F32, false, false><<<gf2, 512, 0, stream>>>(
        ff1, w2T, pbuf, nullptr, nullptr, B * T, C, F / 2, F, F, 1.0f,
        (long long)(F / 2), (long long)(F / 2), (long long)(B * T) * C, 0);

    // out = p0 + p1 + b2 + xres
    ffadd_k<<<dim3(2048), 256, 0, stream>>>(
        (const float4*)pbuf, (const float4*)(pbuf + (long long)(B * T) * C),
        (const float4*)xres, (const float4*)b2, (float4*)d_out,
        (B * T) * C / 4);
}

// Round 8
// 390.789 us; speedup vs baseline: 1.0408x; 1.0408x over previous
//
#include <hip/hip_runtime.h>
#include <hip/hip_bf16.h>

// ---------------------------------------------------------------------------
// Transformer block forward (B=4, T=2048, C=1024, F=4096).
// GEMM engine: 256x256 tile, BK=64, 512 threads (8 waves 2Mx4N, 128x64 per
// wave, acc[8][4]).  2 phases per K-tile (kk = 32-k halves), each:
//   {12 ds_read (8A+4B) | stage A+B of kk for tile t+1 (4 gload_lds) |
//    bar | 32 MFMA | vmcnt(4) bar}
// Drained loads are 2 phases (~1 K-tile) old; never vmcnt(0) mid-loop.
// T2 swizzle: LDS slot s of row r holds global k-slot s^((r>>1)&3); reads
// XOR the same -> every 8-lane octet of a ds_read_b128 hits 8 distinct
// 16B bank-quads (conflict-free), staging stays linear (global_load_lds).
// T5 setprio around the MFMA cluster, T1 bijective XCD block swizzle.
// ---------------------------------------------------------------------------

typedef __bf16 bf16x8_t __attribute__((ext_vector_type(8)));
typedef float f32x4_t __attribute__((ext_vector_type(4)));

__device__ __forceinline__ unsigned short f2bf(float f) {
    unsigned int u = __float_as_uint(f);
    u += 0x7fffu + ((u >> 16) & 1u);   // round-to-nearest-even
    return (unsigned short)(u >> 16);
}
__device__ __forceinline__ float bf2f(unsigned short u) {
    return __uint_as_float((unsigned int)u << 16);
}

__device__ __forceinline__ void gload16(const void* g, void* lds) {
    __builtin_amdgcn_global_load_lds(
        (const __attribute__((address_space(1))) unsigned int*)g,
        (__attribute__((address_space(3))) unsigned int*)lds, 16, 0, 0);
}

#define SB0() __builtin_amdgcn_sched_barrier(0)
#define BAR() asm volatile("s_barrier" ::: "memory")
#define VM4_BAR() asm volatile("s_waitcnt vmcnt(4)\ns_barrier" ::: "memory")
#define VM0_BAR() asm volatile("s_waitcnt vmcnt(0)\ns_barrier" ::: "memory")

enum { EPI_F32 = 0, EPI_BF16 = 1, EPI_BIAS_RELU_BF16 = 2, EPI_RESID_F32 = 3,
       EPI_BIAS_RESID_F32 = 4 };

// C = A @ B^T (+epilogue).  A: [M][lda] bf16 row-major, B: [N][ldb] bf16.
// CSKIP: skip tiles above causal diagonal.  KLIM: Keff = row0+256.
// LDS (bytes): buf*65536 + kk*32768 + op*16384 (op:0=A,1=B); region = 256
// rows x 32 k bf16; 16B chunk c=row*4+s at byte c*16; LDS(row,s) holds
// global k-slot s ^ ((row>>1)&3); reads XOR the same.
template <int EPI, bool CSKIP, bool KLIM>
__global__ __launch_bounds__(512, 2) void gemm256(
    const unsigned short* __restrict__ A,
    const unsigned short* __restrict__ Bm,
    void* __restrict__ Cout,
    const float* __restrict__ bias,
    const float* __restrict__ resid,
    int M, int N, int K, int lda, int ldb, float scale,
    long long batA, long long batB, long long batC, long long batR)
{
    __shared__ __align__(16) unsigned char lds[131072];

    // T1: bijective XCD swizzle of flattened block id (all grids: nwg%8==0)
    const int gx = gridDim.x;
    const int nwg = gx * gridDim.y;
    int bl = blockIdx.y * gx + blockIdx.x;
    bl = (bl & 7) * (nwg >> 3) + (bl >> 3);
    const int bx = bl % gx, by = bl / gx;

    const int row0 = by * 256, col0 = bx * 256;
    if (CSKIP && col0 > row0) return;

    const int bz = blockIdx.z;
    const unsigned short* Ab = A + (long long)bz * batA + (long long)row0 * lda;
    const unsigned short* Bb = Bm + (long long)bz * batB + (long long)col0 * ldb;

    const int tid = threadIdx.x, lane = tid & 63, wid = tid >> 6;
    const int wrM = (wid >> 2) * 128;     // wave row origin (2 x 128)
    const int wcN = (wid & 3) * 64;       // wave col origin (4 x 64)
    const int lr = lane & 15, lg = lane >> 4;

    int Keff = K;
    if (KLIM) { int kl = row0 + 256; Keff = kl < K ? kl : K; }
    const int nkt = Keff >> 6;            // K-tiles of 64 (all calls: nkt>=4)

    // ---- staging: wave covers chunks [wid*128, wid*128+128), 2 per thread
    const int c0 = wid * 128 + lane;
    const int crow = c0 >> 2;                          // +16 for second chunk
    const int sg = (c0 & 3) ^ ((c0 >> 3) & 3);         // T2 source slot (row>>1)
    const unsigned short* gA0 = Ab + (long long)crow * lda + sg * 8;
    const unsigned short* gA1 = gA0 + 16ll * lda;
    const unsigned short* gB0 = Bb + (long long)crow * ldb + sg * 8;
    const unsigned short* gB1 = gB0 + 16ll * ldb;

    // ---- fragment read offsets (bytes within region) ----
    const int sw = (lg ^ ((lr >> 1) & 3)) << 4;        // T2 read swizzle
    const int aoff = (wrM + lr) * 64 + sw;             // + m*1024
    const int boff = 16384 + (wcN + lr) * 64 + sw;     // + n*1024

    f32x4_t acc[8][4];
#pragma unroll
    for (int m = 0; m < 8; ++m)
#pragma unroll
        for (int n = 0; n < 4; ++n)
            acc[m][n] = (f32x4_t){0.f, 0.f, 0.f, 0.f};

    // stage A+B of k-half kk of tile ktn into buffer b (4 gload_lds)
    auto stage2 = [&](int b, int kk, int ktn) {
        const int ke = ktn * 64 + kk * 32;
        unsigned char* uA = lds + b * 65536 + kk * 32768 + wid * 2048;
        unsigned char* uB = uA + 16384;
        gload16(gA0 + ke, uA);
        gload16(gA1 + ke, uA + 1024);
        gload16(gB0 + ke, uB);
        gload16(gB1 + ke, uB + 1024);
    };

    bf16x8_t af[8], bv[4];
    auto dsAB = [&](int b, int kk) {      // 12 ds_read_b128
        const unsigned char* u = lds + b * 65536 + kk * 32768;
#pragma unroll
        for (int m = 0; m < 8; ++m)
            af[m] = *(const bf16x8_t*)(u + aoff + m * 1024);
#pragma unroll
        for (int n = 0; n < 4; ++n)
            bv[n] = *(const bf16x8_t*)(u + boff + n * 1024);
    };
    auto mf32 = [&]() {                   // 32 MFMA
        __builtin_amdgcn_s_setprio(1);
#pragma unroll
        for (int m = 0; m < 8; ++m)
#pragma unroll
            for (int n = 0; n < 4; ++n)
                acc[m][n] = __builtin_amdgcn_mfma_f32_16x16x32_bf16(
                    af[m], bv[n], acc[m][n], 0, 0, 0);
        __builtin_amdgcn_s_setprio(0);
    };

    // prologue: stage tile0 kk0 + kk1 (8 gloads); drain kk0's 4.
    stage2(0, 0, 0); stage2(0, 1, 0);
    VM4_BAR();

    // Ledger (per-thread).  End of ph0(t): outstanding = kk1(t)[4, issued
    // ph1(t-1)] + kk0(t+1)[4, issued ph0(t)] -> vmcnt(4) completes kk1(t)
    // (read next phase).  End of ph1(t): kk0(t+1)+kk1(t+1) -> vmcnt(4)
    // completes kk0(t+1).  Drained loads are always 2 phases old.
    int kt = 0;
    for (; kt < nkt - 1; ++kt) {
        const int buf = kt & 1, nb = buf ^ 1;
        // ph0: kk0
        dsAB(buf, 0);
        stage2(nb, 0, kt + 1);
        BAR(); SB0();
        mf32(); SB0();
        VM4_BAR();
        // ph1: kk1
        dsAB(buf, 1);
        stage2(nb, 1, kt + 1);
        BAR(); SB0();
        mf32(); SB0();
        VM4_BAR();
    }
    {   // tail tile: no staging; drain kk1(last) before its reads
        const int buf = kt & 1;
        dsAB(buf, 0);
        BAR(); SB0();
        mf32(); SB0();
        VM0_BAR();
        dsAB(buf, 1);
        BAR(); SB0();
        mf32(); SB0();
    }

    // ---- epilogue ----
    const int ldc = N;
    float* Cf = (float*)Cout + (long long)bz * batC;
    unsigned short* Cb = (unsigned short*)Cout + (long long)bz * batC;
    const float* R = nullptr;
    if constexpr (EPI == EPI_RESID_F32 || EPI == EPI_BIAS_RESID_F32)
        R = resid + (long long)bz * batR;

#pragma unroll
    for (int m = 0; m < 8; ++m)
#pragma unroll
        for (int n = 0; n < 4; ++n)
#pragma unroll
            for (int j = 0; j < 4; ++j) {
                const int row = row0 + wrM + m * 16 + lg * 4 + j;
                const int col = col0 + wcN + n * 16 + lr;
                const long long idx = (long long)row * ldc + col;
                float v = acc[m][n][j] * scale;
                if constexpr (EPI == EPI_F32) {
                    Cf[idx] = v;
                } else if constexpr (EPI == EPI_BF16) {
                    Cb[idx] = f2bf(v);
                } else if constexpr (EPI == EPI_BIAS_RELU_BF16) {
                    v += bias[col];
                    v = v > 0.f ? v : 0.f;
                    Cb[idx] = f2bf(v);
                } else if constexpr (EPI == EPI_RESID_F32) {
                    Cf[idx] = v + R[idx];
                } else {  // EPI_BIAS_RESID_F32
                    Cf[idx] = v + bias[col] + R[idx];
                }
            }
}

// ------------- transpose + fp32->bf16 convert: in [R][Cc] -> out [Cc][R] ----
__global__ __launch_bounds__(256) void tconv_k(
    const float* __restrict__ in, unsigned short* __restrict__ out,
    int R, int Cc)
{
    __shared__ float t[64][65];
    const int r0 = blockIdx.y * 64, c0 = blockIdx.x * 64;
    const int tid = threadIdx.x;
    const int a = tid >> 4;
    const int b = tid & 15;
#pragma unroll
    for (int i = 0; i < 4; ++i) {
        const int row = a + i * 16;
        float4 v = *(const float4*)(in + (long long)(r0 + row) * Cc + c0 + b * 4);
        t[row][b * 4 + 0] = v.x; t[row][b * 4 + 1] = v.y;
        t[row][b * 4 + 2] = v.z; t[row][b * 4 + 3] = v.w;
    }
    __syncthreads();
#pragma unroll
    for (int i = 0; i < 4; ++i) {
        const int oc = a + i * 16;
        ushort4 o;
        o.x = f2bf(t[b * 4 + 0][oc]);
        o.y = f2bf(t[b * 4 + 1][oc]);
        o.z = f2bf(t[b * 4 + 2][oc]);
        o.w = f2bf(t[b * 4 + 3][oc]);
        *(ushort4*)(out + (long long)(c0 + oc) * R + r0 + b * 4) = o;
    }
}

// ------ bf16 transpose of the v-slice: qkv[8192][3072]@col2048 -> vT[1024][8192]
__global__ __launch_bounds__(256) void vtrans_k(
    const unsigned short* __restrict__ in, unsigned short* __restrict__ out)
{
    __shared__ unsigned short t[64][72];
    const int r0 = blockIdx.x * 64;       // rows of in (time)
    const int c0 = blockIdx.y * 64;       // cols of v (channel)
    const int tid = threadIdx.x;
#pragma unroll
    for (int i = 0; i < 2; ++i) {
        const int ch = tid * 2 + i;       // 0..511
        const int row = ch >> 3, cs = ch & 7;
        int4 v = *(const int4*)(in + (long long)(r0 + row) * 3072 + 2048 + c0 + cs * 8);
        *(int4*)&t[row][cs * 8] = v;      // 144B rows -> 16B-aligned slots
    }
    __syncthreads();
#pragma unroll
    for (int i = 0; i < 2; ++i) {
        const int w = tid * 2 + i;
        const int oc = w >> 3, orc = w & 7;
        unsigned short tmp[8];
#pragma unroll
        for (int j = 0; j < 8; ++j) tmp[j] = t[orc * 8 + j][oc];
        *(int4*)(out + (long long)(c0 + oc) * 8192 + r0 + orc * 8) = *(const int4*)tmp;
    }
}

// ---------------- LayerNorm: one wave per 1024-elem row ---------------------
__global__ __launch_bounds__(256) void ln_k(
    const float* __restrict__ x, const float* __restrict__ g,
    const float* __restrict__ be, unsigned short* __restrict__ out)
{
    const int wv = threadIdx.x >> 6, lane = threadIdx.x & 63;
    const long long row = blockIdx.x * 4 + wv;
    const float* xr = x + row * 1024;
    float4 v[4];
    float s = 0.f, q = 0.f;
#pragma unroll
    for (int j = 0; j < 4; ++j) {
        v[j] = *(const float4*)(xr + j * 256 + lane * 4);
        s += v[j].x + v[j].y + v[j].z + v[j].w;
        q += v[j].x * v[j].x + v[j].y * v[j].y + v[j].z * v[j].z + v[j].w * v[j].w;
    }
#pragma unroll
    for (int off = 32; off > 0; off >>= 1) {
        s += __shfl_xor(s, off);
        q += __shfl_xor(q, off);
    }
    const float mean = s * (1.0f / 1024.0f);
    const float var  = q * (1.0f / 1024.0f) - mean * mean;
    const float rstd = rsqrtf(var + 1e-5f);
#pragma unroll
    for (int j = 0; j < 4; ++j) {
        float4 gv = *(const float4*)(g + j * 256 + lane * 4);
        float4 bv = *(const float4*)(be + j * 256 + lane * 4);
        ushort4 o;
        o.x = f2bf((v[j].x - mean) * rstd * gv.x + bv.x);
        o.y = f2bf((v[j].y - mean) * rstd * gv.y + bv.y);
        o.z = f2bf((v[j].z - mean) * rstd * gv.z + bv.z);
        o.w = f2bf((v[j].w - mean) * rstd * gv.w + bv.w);
        *(ushort4*)(out + row * 1024 + j * 256 + lane * 4) = o;
    }
}

// ------------- causal row softmax: S bf16 -> P bf16 (zero-padded) ----------
__global__ __launch_bounds__(256) void softmax_k(
    const unsigned short* __restrict__ S, unsigned short* __restrict__ P, int T)
{
    __shared__ float rowl[2048];
    __shared__ float sred[4];
    const int t = blockIdx.x;
    const long long base = ((long long)blockIdx.y * T + t) * (long long)T;
    const unsigned short* srow = S + base;
    unsigned short* prow = P + base;
    const int n = t + 1;                       // valid causal length
    const int lim = ((t >> 8) + 1) << 8;       // zero-fill to 256 boundary
    const int tid = threadIdx.x;

    const int n8 = n >> 3;
    for (int i = tid; i < n8; i += 256) {
        int4 r = ((const int4*)srow)[i];
        const unsigned short* u = (const unsigned short*)&r;
#pragma unroll
        for (int j = 0; j < 8; ++j) rowl[i * 8 + j] = bf2f(u[j]);
    }
    for (int i = (n8 << 3) + tid; i < n; i += 256) rowl[i] = bf2f(srow[i]);
    __syncthreads();

    float mx = -3.0e38f;
    for (int i = tid; i < n; i += 256) mx = fmaxf(mx, rowl[i]);
#pragma unroll
    for (int off = 32; off > 0; off >>= 1) mx = fmaxf(mx, __shfl_xor(mx, off));
    if ((tid & 63) == 0) sred[tid >> 6] = mx;
    __syncthreads();
    mx = fmaxf(fmaxf(sred[0], sred[1]), fmaxf(sred[2], sred[3]));
    __syncthreads();

    float sum = 0.f;
    for (int i = tid; i < n; i += 256) {
        float e = __expf(rowl[i] - mx);
        rowl[i] = e;
        sum += e;
    }
#pragma unroll
    for (int off = 32; off > 0; off >>= 1) sum += __shfl_xor(sum, off);
    if ((tid & 63) == 0) sred[tid >> 6] = sum;
    __syncthreads();
    sum = sred[0] + sred[1] + sred[2] + sred[3];
    const float inv = 1.0f / sum;

    for (int i = tid; i < n; i += 256) prow[i] = f2bf(rowl[i] * inv);
    for (int i = n + tid; i < lim; i += 256) prow[i] = 0;
}

// -------- ff2 finalize: out = p0 + p1 + bias[col] + xres (all fp32) --------
__global__ __launch_bounds__(256) void ffadd_k(
    const float4* __restrict__ p0, const float4* __restrict__ p1,
    const float4* __restrict__ xr, const float4* __restrict__ b2,
    float4* __restrict__ out, int n4)
{
    int i = blockIdx.x * 256 + threadIdx.x;
    const int stride = gridDim.x * 256;
    for (; i < n4; i += stride) {
        float4 a = p0[i], b = p1[i], c = xr[i], d = b2[i & 255];
        float4 o;
        o.x = a.x + b.x + c.x + d.x;
        o.y = a.y + b.y + c.y + d.y;
        o.z = a.z + b.z + c.z + d.z;
        o.w = a.w + b.w + c.w + d.w;
        out[i] = o;
    }
}

// ---------------------------------------------------------------------------
extern "C" void kernel_launch(void* const* d_in, const int* in_sizes, int n_in,
                              void* d_out, int out_size, void* d_ws, size_t ws_size,
                              hipStream_t stream)
{
    const int B = 4, T = 2048, C = 1024, F = 4096;
    const float* x   = (const float*)d_in[0];
    const float* Wk  = (const float*)d_in[1];
    const float* Wq  = (const float*)d_in[2];
    const float* Wv  = (const float*)d_in[3];
    const float* W1  = (const float*)d_in[4];
    const float* b1  = (const float*)d_in[5];
    const float* W2  = (const float*)d_in[6];
    const float* b2  = (const float*)d_in[7];
    const float* g1  = (const float*)d_in[8];
    const float* be1 = (const float*)d_in[9];
    const float* g2  = (const float*)d_in[10];
    const float* be2 = (const float*)d_in[11];

    char* ws = (char*)d_ws;
    const size_t MB = 1ull << 20;
    unsigned short* h     = (unsigned short*)(ws + 0);         // 16 MiB
    unsigned short* qkv   = (unsigned short*)(ws + 16 * MB);   // 48 MiB [8192][3072]
    unsigned short* vT    = (unsigned short*)(ws + 64 * MB);   // 16 MiB [1024][8192]
    float*          pbuf  = (float*)(ws + 16 * MB);            // 64 MiB (aliases qkv+vT; used after pv)
    float*          xres  = (float*)(ws + 80 * MB);            // 32 MiB
    unsigned short* S     = (unsigned short*)(ws + 112 * MB);  // 32 MiB bf16 [B][T][T]
    unsigned short* P     = (unsigned short*)(ws + 144 * MB);  // 32 MiB
    unsigned short* ff1   = (unsigned short*)(ws + 112 * MB);  // 64 MiB (aliases S+P; used after pv)
    unsigned short* wqkvT = (unsigned short*)(ws + 176 * MB);  // 6 MiB [3C][C]
    unsigned short* w1T   = (unsigned short*)(ws + 182 * MB);  // 8 MiB [F][C]
    unsigned short* w2T   = (unsigned short*)(ws + 190 * MB);  // 8 MiB [C][F]  (end 198 MiB)

    // transposed weight converts (q,k,v fused into wqkvT)
    tconv_k<<<dim3(16, 16), 256, 0, stream>>>(Wq, wqkvT, C, C);
    tconv_k<<<dim3(16, 16), 256, 0, stream>>>(Wk, wqkvT + C * C, C, C);
    tconv_k<<<dim3(16, 16), 256, 0, stream>>>(Wv, wqkvT + 2 * C * C, C, C);
    tconv_k<<<dim3(64, 16), 256, 0, stream>>>(W1, w1T, C, F);
    tconv_k<<<dim3(16, 64), 256, 0, stream>>>(W2, w2T, F, C);

    // LN1
    ln_k<<<dim3(B * T / 4), 256, 0, stream>>>(x, g1, be1, h);

    // [q|k|v] = h @ [Wq|Wk|Wv]   (M=8192, N=3072, K=1024) -> 384 blocks
    dim3 gqkv(3 * C / 256, (B * T) / 256, 1);
    gemm256<EPI_BF16, false, false><<<gqkv, 512, 0, stream>>>(
        h, wqkvT, qkv, nullptr, nullptr, B * T, 3 * C, C, C, C, 1.0f, 0, 0, 0, 0);

    // vT = transpose of v-slice
    vtrans_k<<<dim3(B * T / 64, C / 64), 256, 0, stream>>>(qkv, vT);

    // S = q @ k^T / 32 (bf16 out; causal tiles only) -> 144 alive
    dim3 gsc(T / 256, T / 256, B);
    gemm256<EPI_BF16, true, false><<<gsc, 512, 0, stream>>>(
        qkv, qkv + C, S, nullptr, nullptr, T, T, C, 3 * C, 3 * C, 0.03125f,
        (long long)T * 3 * C, (long long)T * 3 * C, (long long)T * T, 0);

    // P = causal softmax(S)
    softmax_k<<<dim3(T, B), 256, 0, stream>>>(S, P, T);

    // xres = x + P @ v  (B = vT [C][8192], batch col-offset T) -> 128 blocks
    dim3 gsa(C / 256, T / 256, B);
    gemm256<EPI_RESID_F32, false, true><<<gsa, 512, 0, stream>>>(
        P, vT, xres, nullptr, x, T, C, T, T, B * T, 1.0f,
        (long long)T * T, (long long)T, (long long)T * C, (long long)T * C);

    // LN2
    ln_k<<<dim3(B * T / 4), 256, 0, stream>>>(xres, g2, be2, h);

    // ff1 = relu(h @ W1 + b1)   (M=8192, N=4096, K=1024) -> 512 blocks
    dim3 gf1(F / 256, (B * T) / 256, 1);
    gemm256<EPI_BIAS_RELU_BF16, false, false><<<gf1, 512, 0, stream>>>(
        h, w1T, ff1, b1, nullptr, B * T, F, C, C, C, 1.0f, 0, 0, 0, 0);

    // ff2 split-K z=2: partials = ff1[:, z*2048:] @ W2[z*2048:, :] -> 256 blocks
    dim3 gf2(C / 256, (B * T) / 256, 2);
    gemm256<EPI_F32, false, false><<<gf2, 512, 0, stream>>>(
        ff1, w2T, pbuf, nullptr, nullptr, B * T, C, F / 2, F, F, 1.0f,
        (long long)(F / 2), (long long)(F / 2), (long long)(B * T) * C, 0);

    // out = p0 + p1 + b2 + xres
    ffadd_k<<<dim3(2048), 256, 0, stream>>>(
        (const float4*)pbuf, (const float4*)(pbuf + (long long)(B * T) * C),
        (const float4*)xres, (const float4*)b2, (float4*)d_out,
        (B * T) * C / 4);
}

// Round 9
// 390.118 us; speedup vs baseline: 1.0426x; 1.0017x over previous
//
#include <hip/hip_runtime.h>
#include <hip/hip_bf16.h>

// ---------------------------------------------------------------------------
// Transformer block forward (B=4, T=2048, C=1024, F=4096).
// GEMM engine: 256x256 tile, BK=64, 512 threads (8 waves 2Mx4N, 128x64 per
// wave, acc[8][4]).  m201-style 4 phases per K-tile (kk half x m-quad),
// 16 MFMA per phase on ALTERNATING acc quadrants (no acc dependency between
// consecutive phases -> MFMA drain overlaps next phase's ds_reads):
//   ph0: {8 ds_read (A-mq0 + B) | stage r0' | bar+lgkm0 | 16 MFMA mq0 | bar}
//   ph1: {4 ds_read (A-mq1)     | stage r1' | bar+lgkm0 | 16 MFMA mq1 | vm4+bar}
//   ph2/ph3: same for kk1 (stage r2'/r3'; vm4 at end-ph3)
// Counted vmcnt: drained loads are 2-3 phases old; never vmcnt(0) mid-loop.
// T2 swizzle (row>>1)&3: ds_read_b128 conflict-free (verified 0 in r8).
// T5 setprio around MFMA, T1 bijective XCD block swizzle.
// ---------------------------------------------------------------------------

typedef __bf16 bf16x8_t __attribute__((ext_vector_type(8)));
typedef float f32x4_t __attribute__((ext_vector_type(4)));

__device__ __forceinline__ unsigned short f2bf(float f) {
    unsigned int u = __float_as_uint(f);
    u += 0x7fffu + ((u >> 16) & 1u);   // round-to-nearest-even
    return (unsigned short)(u >> 16);
}
__device__ __forceinline__ float bf2f(unsigned short u) {
    return __uint_as_float((unsigned int)u << 16);
}

__device__ __forceinline__ void gload16(const void* g, void* lds) {
    __builtin_amdgcn_global_load_lds(
        (const __attribute__((address_space(1))) unsigned int*)g,
        (__attribute__((address_space(3))) unsigned int*)lds, 16, 0, 0);
}

#define SB0() __builtin_amdgcn_sched_barrier(0)
#define BAR_LGKM() asm volatile("s_barrier\ns_waitcnt lgkmcnt(0)" ::: "memory")
#define BAR() asm volatile("s_barrier" ::: "memory")
#define VM4_BAR() asm volatile("s_waitcnt vmcnt(4)\ns_barrier" ::: "memory")
#define VM0_BAR() asm volatile("s_waitcnt vmcnt(0)\ns_barrier" ::: "memory")

enum { EPI_F32 = 0, EPI_BF16 = 1, EPI_BIAS_RELU_BF16 = 2, EPI_RESID_F32 = 3,
       EPI_BIAS_RESID_F32 = 4 };

// C = A @ B^T (+epilogue).  A: [M][lda] bf16 row-major, B: [N][ldb] bf16.
// CSKIP: skip tiles above causal diagonal.  KLIM: Keff = row0+256.
// LDS (bytes): buf*65536 + kk*32768 + op*16384 (op:0=A,1=B); region = 256
// rows x 32 k bf16; 16B chunk c=row*4+s at byte c*16; LDS(row,s) holds
// global k-slot s ^ ((row>>1)&3); reads XOR the same.
template <int EPI, bool CSKIP, bool KLIM>
__global__ __launch_bounds__(512, 2) void gemm256(
    const unsigned short* __restrict__ A,
    const unsigned short* __restrict__ Bm,
    void* __restrict__ Cout,
    const float* __restrict__ bias,
    const float* __restrict__ resid,
    int M, int N, int K, int lda, int ldb, float scale,
    long long batA, long long batB, long long batC, long long batR)
{
    __shared__ __align__(16) unsigned char lds[131072];

    // T1: bijective XCD swizzle of flattened block id (all grids: nwg%8==0)
    const int gx = gridDim.x;
    const int nwg = gx * gridDim.y;
    int bl = blockIdx.y * gx + blockIdx.x;
    bl = (bl & 7) * (nwg >> 3) + (bl >> 3);
    const int bx = bl % gx, by = bl / gx;

    const int row0 = by * 256, col0 = bx * 256;
    if (CSKIP && col0 > row0) return;

    const int bz = blockIdx.z;
    const unsigned short* Ab = A + (long long)bz * batA + (long long)row0 * lda;
    const unsigned short* Bb = Bm + (long long)bz * batB + (long long)col0 * ldb;

    const int tid = threadIdx.x, lane = tid & 63, wid = tid >> 6;
    const int wrM = (wid >> 2) * 128;     // wave row origin (2 x 128)
    const int wcN = (wid & 3) * 64;       // wave col origin (4 x 64)
    const int lr = lane & 15, lg = lane >> 4;

    int Keff = K;
    if (KLIM) { int kl = row0 + 256; Keff = kl < K ? kl : K; }
    const int nkt = Keff >> 6;            // K-tiles of 64 (all calls: nkt>=4)

    // ---- staging: wave covers chunks [wid*128, wid*128+128), 2 per thread
    const int c0 = wid * 128 + lane;
    const int crow = c0 >> 2;                          // +16 for second chunk
    const int sg = (c0 & 3) ^ ((c0 >> 3) & 3);         // T2 source slot (row>>1)
    const unsigned short* gA0 = Ab + (long long)crow * lda + sg * 8;
    const unsigned short* gA1 = gA0 + 16ll * lda;
    const unsigned short* gB0 = Bb + (long long)crow * ldb + sg * 8;
    const unsigned short* gB1 = gB0 + 16ll * ldb;

    // ---- fragment read offsets (bytes within region) ----
    const int sw = (lg ^ ((lr >> 1) & 3)) << 4;        // T2 read swizzle
    const int aoff = (wrM + lr) * 64 + sw;             // + m*1024
    const int boff = 16384 + (wcN + lr) * 64 + sw;     // + n*1024

    f32x4_t acc[8][4];
#pragma unroll
    for (int m = 0; m < 8; ++m)
#pragma unroll
        for (int n = 0; n < 4; ++n)
            acc[m][n] = (f32x4_t){0.f, 0.f, 0.f, 0.f};

    // stage region r (0=A-kk0,1=B-kk0,2=A-kk1,3=B-kk1) of tile ktn into buf b
    auto stageR = [&](int b, int r, int ktn) {
        const int kk = r >> 1, op = r & 1;
        const int ke = ktn * 64 + kk * 32;
        unsigned char* d = lds + b * 65536 + kk * 32768 + op * 16384 + wid * 2048;
        const unsigned short* g0 = (op ? gB0 : gA0) + ke;
        const unsigned short* g1 = (op ? gB1 : gA1) + ke;
        gload16(g0, d);
        gload16(g1, d + 1024);
    };

    bf16x8_t af[4], bv[4];
    auto dsA4 = [&](int b, int kk, int mq) {           // 4 ds_read_b128
        const unsigned char* u = lds + b * 65536 + kk * 32768;
#pragma unroll
        for (int j = 0; j < 4; ++j)
            af[j] = *(const bf16x8_t*)(u + aoff + (mq * 4 + j) * 1024);
    };
    auto dsB4 = [&](int b, int kk) {                   // 4 ds_read_b128
        const unsigned char* u = lds + b * 65536 + kk * 32768;
#pragma unroll
        for (int n = 0; n < 4; ++n)
            bv[n] = *(const bf16x8_t*)(u + boff + n * 1024);
    };
    auto mf16 = [&](int mq) {                          // 16 MFMA, quad mq
        __builtin_amdgcn_s_setprio(1);
#pragma unroll
        for (int j = 0; j < 4; ++j)
#pragma unroll
            for (int n = 0; n < 4; ++n)
                acc[mq * 4 + j][n] = __builtin_amdgcn_mfma_f32_16x16x32_bf16(
                    af[j], bv[n], acc[mq * 4 + j][n], 0, 0, 0);
        __builtin_amdgcn_s_setprio(0);
    };

    // prologue: stage tile0 fully (r0..r3 = 8 gloads); drain r0,r1 (kk0).
    stageR(0, 0, 0); stageR(0, 1, 0); stageR(0, 2, 0); stageR(0, 3, 0);
    VM4_BAR();

    // Ledger (per-thread, entering ph0(t)): outstanding = r2,r3(t) [4 loads,
    // issued ph2,ph3 of t-1].  ph0:+r0'(2) ->6.  ph1:+r1'(2) ->8, end
    // vmcnt(4) drains r2,r3(t) (read at ph2; 2-3 phases old).  ph2:+r2'(2)
    // ->6.  ph3:+r3'(2) ->8, end vmcnt(4) drains r0',r1' (read ph0(t+1)).
    int kt = 0;
    for (; kt < nkt - 1; ++kt) {
        const int buf = kt & 1, nb = buf ^ 1;
        // ph0: kk0, mq0
        dsA4(buf, 0, 0); dsB4(buf, 0);
        stageR(nb, 0, kt + 1);
        BAR_LGKM(); SB0();
        mf16(0); SB0();
        BAR();
        // ph1: kk0, mq1 (bv reused)
        dsA4(buf, 0, 1);
        stageR(nb, 1, kt + 1);
        BAR_LGKM(); SB0();
        mf16(1); SB0();
        VM4_BAR();
        // ph2: kk1, mq0
        dsA4(buf, 1, 0); dsB4(buf, 1);
        stageR(nb, 2, kt + 1);
        BAR_LGKM(); SB0();
        mf16(0); SB0();
        BAR();
        // ph3: kk1, mq1
        dsA4(buf, 1, 1);
        stageR(nb, 3, kt + 1);
        BAR_LGKM(); SB0();
        mf16(1); SB0();
        VM4_BAR();
    }
    {   // tail tile: no staging; drain r2,r3(tail) at end-ph1
        const int buf = kt & 1;
        dsA4(buf, 0, 0); dsB4(buf, 0);
        BAR_LGKM(); SB0();
        mf16(0); SB0();
        BAR();
        dsA4(buf, 0, 1);
        BAR_LGKM(); SB0();
        mf16(1); SB0();
        VM0_BAR();
        dsA4(buf, 1, 0); dsB4(buf, 1);
        BAR_LGKM(); SB0();
        mf16(0); SB0();
        BAR();
        dsA4(buf, 1, 1);
        BAR_LGKM(); SB0();
        mf16(1); SB0();
    }

    // ---- epilogue ----
    const int ldc = N;
    float* Cf = (float*)Cout + (long long)bz * batC;
    unsigned short* Cb = (unsigned short*)Cout + (long long)bz * batC;
    const float* R = nullptr;
    if constexpr (EPI == EPI_RESID_F32 || EPI == EPI_BIAS_RESID_F32)
        R = resid + (long long)bz * batR;

#pragma unroll
    for (int m = 0; m < 8; ++m)
#pragma unroll
        for (int n = 0; n < 4; ++n)
#pragma unroll
            for (int j = 0; j < 4; ++j) {
                const int row = row0 + wrM + m * 16 + lg * 4 + j;
                const int col = col0 + wcN + n * 16 + lr;
                const long long idx = (long long)row * ldc + col;
                float v = acc[m][n][j] * scale;
                if constexpr (EPI == EPI_F32) {
                    Cf[idx] = v;
                } else if constexpr (EPI == EPI_BF16) {
                    Cb[idx] = f2bf(v);
                } else if constexpr (EPI == EPI_BIAS_RELU_BF16) {
                    v += bias[col];
                    v = v > 0.f ? v : 0.f;
                    Cb[idx] = f2bf(v);
                } else if constexpr (EPI == EPI_RESID_F32) {
                    Cf[idx] = v + R[idx];
                } else {  // EPI_BIAS_RESID_F32
                    Cf[idx] = v + bias[col] + R[idx];
                }
            }
}

// ------------- transpose + fp32->bf16 convert: in [R][Cc] -> out [Cc][R] ----
__global__ __launch_bounds__(256) void tconv_k(
    const float* __restrict__ in, unsigned short* __restrict__ out,
    int R, int Cc)
{
    __shared__ float t[64][65];
    const int r0 = blockIdx.y * 64, c0 = blockIdx.x * 64;
    const int tid = threadIdx.x;
    const int a = tid >> 4;
    const int b = tid & 15;
#pragma unroll
    for (int i = 0; i < 4; ++i) {
        const int row = a + i * 16;
        float4 v = *(const float4*)(in + (long long)(r0 + row) * Cc + c0 + b * 4);
        t[row][b * 4 + 0] = v.x; t[row][b * 4 + 1] = v.y;
        t[row][b * 4 + 2] = v.z; t[row][b * 4 + 3] = v.w;
    }
    __syncthreads();
#pragma unroll
    for (int i = 0; i < 4; ++i) {
        const int oc = a + i * 16;
        ushort4 o;
        o.x = f2bf(t[b * 4 + 0][oc]);
        o.y = f2bf(t[b * 4 + 1][oc]);
        o.z = f2bf(t[b * 4 + 2][oc]);
        o.w = f2bf(t[b * 4 + 3][oc]);
        *(ushort4*)(out + (long long)(c0 + oc) * R + r0 + b * 4) = o;
    }
}

// ------ bf16 transpose of the v-slice: qkv[8192][3072]@col2048 -> vT[1024][8192]
__global__ __launch_bounds__(256) void vtrans_k(
    const unsigned short* __restrict__ in, unsigned short* __restrict__ out)
{
    __shared__ unsigned short t[64][72];
    const int r0 = blockIdx.x * 64;       // rows of in (time)
    const int c0 = blockIdx.y * 64;       // cols of v (channel)
    const int tid = threadIdx.x;
#pragma unroll
    for (int i = 0; i < 2; ++i) {
        const int ch = tid * 2 + i;       // 0..511
        const int row = ch >> 3, cs = ch & 7;
        int4 v = *(const int4*)(in + (long long)(r0 + row) * 3072 + 2048 + c0 + cs * 8);
        *(int4*)&t[row][cs * 8] = v;      // 144B rows -> 16B-aligned slots
    }
    __syncthreads();
#pragma unroll
    for (int i = 0; i < 2; ++i) {
        const int w = tid * 2 + i;
        const int oc = w >> 3, orc = w & 7;
        unsigned short tmp[8];
#pragma unroll
        for (int j = 0; j < 8; ++j) tmp[j] = t[orc * 8 + j][oc];
        *(int4*)(out + (long long)(c0 + oc) * 8192 + r0 + orc * 8) = *(const int4*)tmp;
    }
}

// ---------------- LayerNorm: one wave per 1024-elem row ---------------------
__global__ __launch_bounds__(256) void ln_k(
    const float* __restrict__ x, const float* __restrict__ g,
    const float* __restrict__ be, unsigned short* __restrict__ out)
{
    const int wv = threadIdx.x >> 6, lane = threadIdx.x & 63;
    const long long row = blockIdx.x * 4 + wv;
    const float* xr = x + row * 1024;
    float4 v[4];
    float s = 0.f, q = 0.f;
#pragma unroll
    for (int j = 0; j < 4; ++j) {
        v[j] = *(const float4*)(xr + j * 256 + lane * 4);
        s += v[j].x + v[j].y + v[j].z + v[j].w;
        q += v[j].x * v[j].x + v[j].y * v[j].y + v[j].z * v[j].z + v[j].w * v[j].w;
    }
#pragma unroll
    for (int off = 32; off > 0; off >>= 1) {
        s += __shfl_xor(s, off);
        q += __shfl_xor(q, off);
    }
    const float mean = s * (1.0f / 1024.0f);
    const float var  = q * (1.0f / 1024.0f) - mean * mean;
    const float rstd = rsqrtf(var + 1e-5f);
#pragma unroll
    for (int j = 0; j < 4; ++j) {
        float4 gv = *(const float4*)(g + j * 256 + lane * 4);
        float4 bv = *(const float4*)(be + j * 256 + lane * 4);
        ushort4 o;
        o.x = f2bf((v[j].x - mean) * rstd * gv.x + bv.x);
        o.y = f2bf((v[j].y - mean) * rstd * gv.y + bv.y);
        o.z = f2bf((v[j].z - mean) * rstd * gv.z + bv.z);
        o.w = f2bf((v[j].w - mean) * rstd * gv.w + bv.w);
        *(ushort4*)(out + row * 1024 + j * 256 + lane * 4) = o;
    }
}

// ------------- causal row softmax: S bf16 -> P bf16 (zero-padded) ----------
__global__ __launch_bounds__(256) void softmax_k(
    const unsigned short* __restrict__ S, unsigned short* __restrict__ P, int T)
{
    __shared__ float rowl[2048];
    __shared__ float sred[4];
    const int t = blockIdx.x;
    const long long base = ((long long)blockIdx.y * T + t) * (long long)T;
    const unsigned short* srow = S + base;
    unsigned short* prow = P + base;
    const int n = t + 1;                       // valid causal length
    const int lim = ((t >> 8) + 1) << 8;       // zero-fill to 256 boundary
    const int tid = threadIdx.x;

    const int n8 = n >> 3;
    for (int i = tid; i < n8; i += 256) {
        int4 r = ((const int4*)srow)[i];
        const unsigned short* u = (const unsigned short*)&r;
#pragma unroll
        for (int j = 0; j < 8; ++j) rowl[i * 8 + j] = bf2f(u[j]);
    }
    for (int i = (n8 << 3) + tid; i < n; i += 256) rowl[i] = bf2f(srow[i]);
    __syncthreads();

    float mx = -3.0e38f;
    for (int i = tid; i < n; i += 256) mx = fmaxf(mx, rowl[i]);
#pragma unroll
    for (int off = 32; off > 0; off >>= 1) mx = fmaxf(mx, __shfl_xor(mx, off));
    if ((tid & 63) == 0) sred[tid >> 6] = mx;
    __syncthreads();
    mx = fmaxf(fmaxf(sred[0], sred[1]), fmaxf(sred[2], sred[3]));
    __syncthreads();

    float sum = 0.f;
    for (int i = tid; i < n; i += 256) {
        float e = __expf(rowl[i] - mx);
        rowl[i] = e;
        sum += e;
    }
#pragma unroll
    for (int off = 32; off > 0; off >>= 1) sum += __shfl_xor(sum, off);
    if ((tid & 63) == 0) sred[tid >> 6] = sum;
    __syncthreads();
    sum = sred[0] + sred[1] + sred[2] + sred[3];
    const float inv = 1.0f / sum;

    for (int i = tid; i < n; i += 256) prow[i] = f2bf(rowl[i] * inv);
    for (int i = n + tid; i < lim; i += 256) prow[i] = 0;
}

// -------- ff2 finalize: out = p0 + p1 + bias[col] + xres (all fp32) --------
__global__ __launch_bounds__(256) void ffadd_k(
    const float4* __restrict__ p0, const float4* __restrict__ p1,
    const float4* __restrict__ xr, const float4* __restrict__ b2,
    float4* __restrict__ out, int n4)
{
    int i = blockIdx.x * 256 + threadIdx.x;
    const int stride = gridDim.x * 256;
    for (; i < n4; i += stride) {
        float4 a = p0[i], b = p1[i], c = xr[i], d = b2[i & 255];
        float4 o;
        o.x = a.x + b.x + c.x + d.x;
        o.y = a.y + b.y + c.y + d.y;
        o.z = a.z + b.z + c.z + d.z;
        o.w = a.w + b.w + c.w + d.w;
        out[i] = o;
    }
}

// ---------------------------------------------------------------------------
extern "C" void kernel_launch(void* const* d_in, const int* in_sizes, int n_in,
                              void* d_out, int out_size, void* d_ws, size_t ws_size,
                              hipStream_t stream)
{
    const int B = 4, T = 2048, C = 1024, F = 4096;
    const float* x   = (const float*)d_in[0];
    const float* Wk  = (const float*)d_in[1];
    const float* Wq  = (const float*)d_in[2];
    const float* Wv  = (const float*)d_in[3];
    const float* W1  = (const float*)d_in[4];
    const float* b1  = (const float*)d_in[5];
    const float* W2  = (const float*)d_in[6];
    const float* b2  = (const float*)d_in[7];
    const float* g1  = (const float*)d_in[8];
    const float* be1 = (const float*)d_in[9];
    const float* g2  = (const float*)d_in[10];
    const float* be2 = (const float*)d_in[11];

    char* ws = (char*)d_ws;
    const size_t MB = 1ull << 20;
    unsigned short* h     = (unsigned short*)(ws + 0);         // 16 MiB
    unsigned short* qkv   = (unsigned short*)(ws + 16 * MB);   // 48 MiB [8192][3072]
    unsigned short* vT    = (unsigned short*)(ws + 64 * MB);   // 16 MiB [1024][8192]
    float*          pbuf  = (float*)(ws + 16 * MB);            // 64 MiB (aliases qkv+vT; used after pv)
    float*          xres  = (float*)(ws + 80 * MB);            // 32 MiB
    unsigned short* S     = (unsigned short*)(ws + 112 * MB);  // 32 MiB bf16 [B][T][T]
    unsigned short* P     = (unsigned short*)(ws + 144 * MB);  // 32 MiB
    unsigned short* ff1   = (unsigned short*)(ws + 112 * MB);  // 64 MiB (aliases S+P; used after pv)
    unsigned short* wqkvT = (unsigned short*)(ws + 176 * MB);  // 6 MiB [3C][C]
    unsigned short* w1T   = (unsigned short*)(ws + 182 * MB);  // 8 MiB [F][C]
    unsigned short* w2T   = (unsigned short*)(ws + 190 * MB);  // 8 MiB [C][F]  (end 198 MiB)

    // transposed weight converts (q,k,v fused into wqkvT)
    tconv_k<<<dim3(16, 16), 256, 0, stream>>>(Wq, wqkvT, C, C);
    tconv_k<<<dim3(16, 16), 256, 0, stream>>>(Wk, wqkvT + C * C, C, C);
    tconv_k<<<dim3(16, 16), 256, 0, stream>>>(Wv, wqkvT + 2 * C * C, C, C);
    tconv_k<<<dim3(64, 16), 256, 0, stream>>>(W1, w1T, C, F);
    tconv_k<<<dim3(16, 64), 256, 0, stream>>>(W2, w2T, F, C);

    // LN1
    ln_k<<<dim3(B * T / 4), 256, 0, stream>>>(x, g1, be1, h);

    // [q|k|v] = h @ [Wq|Wk|Wv]   (M=8192, N=3072, K=1024) -> 384 blocks
    dim3 gqkv(3 * C / 256, (B * T) / 256, 1);
    gemm256<EPI_BF16, false, false><<<gqkv, 512, 0, stream>>>(
        h, wqkvT, qkv, nullptr, nullptr, B * T, 3 * C, C, C, C, 1.0f, 0, 0, 0, 0);

    // vT = transpose of v-slice
    vtrans_k<<<dim3(B * T / 64, C / 64), 256, 0, stream>>>(qkv, vT);

    // S = q @ k^T / 32 (bf16 out; causal tiles only) -> 144 alive
    dim3 gsc(T / 256, T / 256, B);
    gemm256<EPI_BF16, true, false><<<gsc, 512, 0, stream>>>(
        qkv, qkv + C, S, nullptr, nullptr, T, T, C, 3 * C, 3 * C, 0.03125f,
        (long long)T * 3 * C, (long long)T * 3 * C, (long long)T * T, 0);

    // P = causal softmax(S)
    softmax_k<<<dim3(T, B), 256, 0, stream>>>(S, P, T);

    // xres = x + P @ v  (B = vT [C][8192], batch col-offset T) -> 128 blocks
    dim3 gsa(C / 256, T / 256, B);
    gemm256<EPI_RESID_F32, false, true><<<gsa, 512, 0, stream>>>(
        P, vT, xres, nullptr, x, T, C, T, T, B * T, 1.0f,
        (long long)T * T, (long long)T, (long long)T * C, (long long)T * C);

    // LN2
    ln_k<<<dim3(B * T / 4), 256, 0, stream>>>(xres, g2, be2, h);

    // ff1 = relu(h @ W1 + b1)   (M=8192, N=4096, K=1024) -> 512 blocks
    dim3 gf1(F / 256, (B * T) / 256, 1);
    gemm256<EPI_BIAS_RELU_BF16, false, false><<<gf1, 512, 0, stream>>>(
        h, w1T, ff1, b1, nullptr, B * T, F, C, C, C, 1.0f, 0, 0, 0, 0);

    // ff2 split-K z=2: partials = ff1[:, z*2048:] @ W2[z*2048:, :] -> 256 blocks
    dim3 gf2(C / 256, (B * T) / 256, 2);
    gemm256<EPI_F32, false, false><<<gf2, 512, 0, stream>>>(
        ff1, w2T, pbuf, nullptr, nullptr, B * T, C, F / 2, F, F, 1.0f,
        (long long)(F / 2), (long long)(F / 2), (long long)(B * T) * C, 0);

    // out = p0 + p1 + b2 + xres
    ffadd_k<<<dim3(2048), 256, 0, stream>>>(
        (const float4*)pbuf, (const float4*)(pbuf + (long long)(B * T) * C),
        (const float4*)xres, (const float4*)b2, (float4*)d_out,
        (B * T) * C / 4);
}

// Round 10
// 380.970 us; speedup vs baseline: 1.0677x; 1.0240x over previous
//
#include <hip/hip_runtime.h>
#include <hip/hip_bf16.h>

// ---------------------------------------------------------------------------
// Transformer block forward (B=4, T=2048, C=1024, F=4096).
// GEMM engine: 128x128 tile, BK=64, 256 threads (4 waves 2Mx2N, 64x64 per
// wave, acc[4][4]).  LDS 64 KiB -> 2 blocks/CU: two independent barrier
// domains per CU overlap each other's read/drain/epilogue stalls (the m97
// implicit-overlap mechanism, now with conflict-free swizzled LDS and a
// counted-vmcnt ledger).  2 phases per K-tile (kk halves):
//   ph: {8 ds_read (4A+4B) | stage kk of tile t+1 (4 gload_lds) |
//        bar+lgkm0 | 16 MFMA | vmcnt(4)+bar}
// Drained loads are 2 phases old; never vmcnt(0) mid-loop.
// T2 swizzle (row>>1)&3: ds_read_b128 conflict-free (verified 0 in r8/r9).
// T5 setprio, T1 bijective XCD block swizzle.
// ff2 runs as a plain GEMM (512 blocks) with fused bias+residual epilogue.
// ---------------------------------------------------------------------------

typedef __bf16 bf16x8_t __attribute__((ext_vector_type(8)));
typedef float f32x4_t __attribute__((ext_vector_type(4)));

__device__ __forceinline__ unsigned short f2bf(float f) {
    unsigned int u = __float_as_uint(f);
    u += 0x7fffu + ((u >> 16) & 1u);   // round-to-nearest-even
    return (unsigned short)(u >> 16);
}
__device__ __forceinline__ float bf2f(unsigned short u) {
    return __uint_as_float((unsigned int)u << 16);
}

__device__ __forceinline__ void gload16(const void* g, void* lds) {
    __builtin_amdgcn_global_load_lds(
        (const __attribute__((address_space(1))) unsigned int*)g,
        (__attribute__((address_space(3))) unsigned int*)lds, 16, 0, 0);
}

#define SB0() __builtin_amdgcn_sched_barrier(0)
#define BAR_LGKM() asm volatile("s_barrier\ns_waitcnt lgkmcnt(0)" ::: "memory")
#define VM4_BAR() asm volatile("s_waitcnt vmcnt(4)\ns_barrier" ::: "memory")
#define VM0_BAR() asm volatile("s_waitcnt vmcnt(0)\ns_barrier" ::: "memory")

enum { EPI_F32 = 0, EPI_BF16 = 1, EPI_BIAS_RELU_BF16 = 2, EPI_RESID_F32 = 3,
       EPI_BIAS_RESID_F32 = 4 };

// C = A @ B^T (+epilogue).  A: [M][lda] bf16 row-major, B: [N][ldb] bf16.
// CSKIP: skip tiles above causal diagonal.  KLIM: Keff = row0+128.
// LDS (bytes): buf*32768 + kk*16384 + op*8192 (op:0=A,1=B); region = 128
// rows x 32 k bf16; 16B chunk c=row*4+s at byte c*16; LDS(row,s) holds
// global k-slot s ^ ((row>>1)&3); reads XOR the same.
template <int EPI, bool CSKIP, bool KLIM>
__global__ __launch_bounds__(256, 2) void gemm128(
    const unsigned short* __restrict__ A,
    const unsigned short* __restrict__ Bm,
    void* __restrict__ Cout,
    const float* __restrict__ bias,
    const float* __restrict__ resid,
    int M, int N, int K, int lda, int ldb, float scale,
    long long batA, long long batB, long long batC, long long batR)
{
    __shared__ __align__(16) unsigned char lds[65536];

    // T1: bijective XCD swizzle of flattened block id (all grids: nwg%8==0)
    const int gx = gridDim.x;
    const int nwg = gx * gridDim.y;
    int bl = blockIdx.y * gx + blockIdx.x;
    bl = (bl & 7) * (nwg >> 3) + (bl >> 3);
    const int bx = bl % gx, by = bl / gx;

    const int row0 = by * 128, col0 = bx * 128;
    if (CSKIP && col0 > row0) return;

    const int bz = blockIdx.z;
    const unsigned short* Ab = A + (long long)bz * batA + (long long)row0 * lda;
    const unsigned short* Bb = Bm + (long long)bz * batB + (long long)col0 * ldb;

    const int tid = threadIdx.x, lane = tid & 63, wid = tid >> 6;
    const int wrM = (wid >> 1) * 64;      // wave row origin (2 x 64)
    const int wcN = (wid & 1) * 64;       // wave col origin (2 x 64)
    const int lr = lane & 15, lg = lane >> 4;

    int Keff = K;
    if (KLIM) { int kl = row0 + 128; Keff = kl < K ? kl : K; }
    const int nkt = Keff >> 6;            // K-tiles of 64 (all calls: nkt>=2)

    // ---- staging: per region (128x32 = 512 chunks) each thread covers
    // chunks c0 = wid*128+lane and c0+64; row = c>>2, slot (c&3)^((row>>1)&3)
    const int c0 = wid * 128 + lane;
    const int crow = c0 >> 2;                          // +16 for second chunk
    const int sg = (c0 & 3) ^ ((c0 >> 3) & 3);
    const unsigned short* gA0 = Ab + (long long)crow * lda + sg * 8;
    const unsigned short* gA1 = gA0 + 16ll * lda;
    const unsigned short* gB0 = Bb + (long long)crow * ldb + sg * 8;
    const unsigned short* gB1 = gB0 + 16ll * ldb;

    // ---- fragment read offsets (bytes within region) ----
    const int sw = (lg ^ ((lr >> 1) & 3)) << 4;        // T2 read swizzle
    const int aoff = (wrM + lr) * 64 + sw;             // + m*1024
    const int boff = 8192 + (wcN + lr) * 64 + sw;      // + n*1024

    f32x4_t acc[4][4];
#pragma unroll
    for (int m = 0; m < 4; ++m)
#pragma unroll
        for (int n = 0; n < 4; ++n)
            acc[m][n] = (f32x4_t){0.f, 0.f, 0.f, 0.f};

    // stage A+B of k-half kk of tile ktn into buffer b (4 gload_lds)
    auto stage2 = [&](int b, int kk, int ktn) {
        const int ke = ktn * 64 + kk * 32;
        unsigned char* uA = lds + b * 32768 + kk * 16384 + wid * 2048;
        unsigned char* uB = uA + 8192;
        gload16(gA0 + ke, uA);
        gload16(gA1 + ke, uA + 1024);
        gload16(gB0 + ke, uB);
        gload16(gB1 + ke, uB + 1024);
    };

    bf16x8_t af[4], bv[4];
    auto dsAB = [&](int b, int kk) {      // 8 ds_read_b128
        const unsigned char* u = lds + b * 32768 + kk * 16384;
#pragma unroll
        for (int m = 0; m < 4; ++m)
            af[m] = *(const bf16x8_t*)(u + aoff + m * 1024);
#pragma unroll
        for (int n = 0; n < 4; ++n)
            bv[n] = *(const bf16x8_t*)(u + boff + n * 1024);
    };
    auto mf16 = [&]() {                   // 16 MFMA
        __builtin_amdgcn_s_setprio(1);
#pragma unroll
        for (int m = 0; m < 4; ++m)
#pragma unroll
            for (int n = 0; n < 4; ++n)
                acc[m][n] = __builtin_amdgcn_mfma_f32_16x16x32_bf16(
                    af[m], bv[n], acc[m][n], 0, 0, 0);
        __builtin_amdgcn_s_setprio(0);
    };

    // prologue: stage tile0 kk0+kk1 (8 gloads); drain kk0's 4.
    stage2(0, 0, 0); stage2(0, 1, 0);
    VM4_BAR();

    // Ledger (per-thread, entering ph0(t)): outstanding = kk1(t) [4, issued
    // ph1(t-1)].  ph0: +kk0(t+1) -> 8; end vmcnt(4) drains kk1(t) (read at
    // ph1; 2 phases old).  ph1: +kk1(t+1) -> 8; end vmcnt(4) drains kk0(t+1)
    // (read ph0(t+1)).
    int kt = 0;
    for (; kt < nkt - 1; ++kt) {
        const int buf = kt & 1, nb = buf ^ 1;
        // ph0: kk0
        dsAB(buf, 0);
        stage2(nb, 0, kt + 1);
        BAR_LGKM(); SB0();
        mf16(); SB0();
        VM4_BAR();
        // ph1: kk1
        dsAB(buf, 1);
        stage2(nb, 1, kt + 1);
        BAR_LGKM(); SB0();
        mf16(); SB0();
        VM4_BAR();
    }
    {   // tail tile: no staging; drain kk1(tail) after ph0
        const int buf = kt & 1;
        dsAB(buf, 0);
        BAR_LGKM(); SB0();
        mf16(); SB0();
        VM0_BAR();
        dsAB(buf, 1);
        BAR_LGKM(); SB0();
        mf16(); SB0();
    }

    // ---- epilogue ----
    const int ldc = N;
    float* Cf = (float*)Cout + (long long)bz * batC;
    unsigned short* Cb = (unsigned short*)Cout + (long long)bz * batC;
    const float* R = nullptr;
    if constexpr (EPI == EPI_RESID_F32 || EPI == EPI_BIAS_RESID_F32)
        R = resid + (long long)bz * batR;

#pragma unroll
    for (int m = 0; m < 4; ++m)
#pragma unroll
        for (int n = 0; n < 4; ++n)
#pragma unroll
            for (int j = 0; j < 4; ++j) {
                const int row = row0 + wrM + m * 16 + lg * 4 + j;
                const int col = col0 + wcN + n * 16 + lr;
                const long long idx = (long long)row * ldc + col;
                float v = acc[m][n][j] * scale;
                if constexpr (EPI == EPI_F32) {
                    Cf[idx] = v;
                } else if constexpr (EPI == EPI_BF16) {
                    Cb[idx] = f2bf(v);
                } else if constexpr (EPI == EPI_BIAS_RELU_BF16) {
                    v += bias[col];
                    v = v > 0.f ? v : 0.f;
                    Cb[idx] = f2bf(v);
                } else if constexpr (EPI == EPI_RESID_F32) {
                    Cf[idx] = v + R[idx];
                } else {  // EPI_BIAS_RESID_F32
                    Cf[idx] = v + bias[col] + R[idx];
                }
            }
}

// ------------- transpose + fp32->bf16 convert: in [R][Cc] -> out [Cc][R] ----
__global__ __launch_bounds__(256) void tconv_k(
    const float* __restrict__ in, unsigned short* __restrict__ out,
    int R, int Cc)
{
    __shared__ float t[64][65];
    const int r0 = blockIdx.y * 64, c0 = blockIdx.x * 64;
    const int tid = threadIdx.x;
    const int a = tid >> 4;
    const int b = tid & 15;
#pragma unroll
    for (int i = 0; i < 4; ++i) {
        const int row = a + i * 16;
        float4 v = *(const float4*)(in + (long long)(r0 + row) * Cc + c0 + b * 4);
        t[row][b * 4 + 0] = v.x; t[row][b * 4 + 1] = v.y;
        t[row][b * 4 + 2] = v.z; t[row][b * 4 + 3] = v.w;
    }
    __syncthreads();
#pragma unroll
    for (int i = 0; i < 4; ++i) {
        const int oc = a + i * 16;
        ushort4 o;
        o.x = f2bf(t[b * 4 + 0][oc]);
        o.y = f2bf(t[b * 4 + 1][oc]);
        o.z = f2bf(t[b * 4 + 2][oc]);
        o.w = f2bf(t[b * 4 + 3][oc]);
        *(ushort4*)(out + (long long)(c0 + oc) * R + r0 + b * 4) = o;
    }
}

// ------ bf16 transpose of the v-slice: qkv[8192][3072]@col2048 -> vT[1024][8192]
__global__ __launch_bounds__(256) void vtrans_k(
    const unsigned short* __restrict__ in, unsigned short* __restrict__ out)
{
    __shared__ unsigned short t[64][72];
    const int r0 = blockIdx.x * 64;       // rows of in (time)
    const int c0 = blockIdx.y * 64;       // cols of v (channel)
    const int tid = threadIdx.x;
#pragma unroll
    for (int i = 0; i < 2; ++i) {
        const int ch = tid * 2 + i;       // 0..511
        const int row = ch >> 3, cs = ch & 7;
        int4 v = *(const int4*)(in + (long long)(r0 + row) * 3072 + 2048 + c0 + cs * 8);
        *(int4*)&t[row][cs * 8] = v;      // 144B rows -> 16B-aligned slots
    }
    __syncthreads();
#pragma unroll
    for (int i = 0; i < 2; ++i) {
        const int w = tid * 2 + i;
        const int oc = w >> 3, orc = w & 7;
        unsigned short tmp[8];
#pragma unroll
        for (int j = 0; j < 8; ++j) tmp[j] = t[orc * 8 + j][oc];
        *(int4*)(out + (long long)(c0 + oc) * 8192 + r0 + orc * 8) = *(const int4*)tmp;
    }
}

// ---------------- LayerNorm: one wave per 1024-elem row ---------------------
__global__ __launch_bounds__(256) void ln_k(
    const float* __restrict__ x, const float* __restrict__ g,
    const float* __restrict__ be, unsigned short* __restrict__ out)
{
    const int wv = threadIdx.x >> 6, lane = threadIdx.x & 63;
    const long long row = blockIdx.x * 4 + wv;
    const float* xr = x + row * 1024;
    float4 v[4];
    float s = 0.f, q = 0.f;
#pragma unroll
    for (int j = 0; j < 4; ++j) {
        v[j] = *(const float4*)(xr + j * 256 + lane * 4);
        s += v[j].x + v[j].y + v[j].z + v[j].w;
        q += v[j].x * v[j].x + v[j].y * v[j].y + v[j].z * v[j].z + v[j].w * v[j].w;
    }
#pragma unroll
    for (int off = 32; off > 0; off >>= 1) {
        s += __shfl_xor(s, off);
        q += __shfl_xor(q, off);
    }
    const float mean = s * (1.0f / 1024.0f);
    const float var  = q * (1.0f / 1024.0f) - mean * mean;
    const float rstd = rsqrtf(var + 1e-5f);
#pragma unroll
    for (int j = 0; j < 4; ++j) {
        float4 gv = *(const float4*)(g + j * 256 + lane * 4);
        float4 bv = *(const float4*)(be + j * 256 + lane * 4);
        ushort4 o;
        o.x = f2bf((v[j].x - mean) * rstd * gv.x + bv.x);
        o.y = f2bf((v[j].y - mean) * rstd * gv.y + bv.y);
        o.z = f2bf((v[j].z - mean) * rstd * gv.z + bv.z);
        o.w = f2bf((v[j].w - mean) * rstd * gv.w + bv.w);
        *(ushort4*)(out + row * 1024 + j * 256 + lane * 4) = o;
    }
}

// ------------- causal row softmax: S bf16 -> P bf16 (zero-padded) ----------
__global__ __launch_bounds__(256) void softmax_k(
    const unsigned short* __restrict__ S, unsigned short* __restrict__ P, int T)
{
    __shared__ float rowl[2048];
    __shared__ float sred[4];
    const int t = blockIdx.x;
    const long long base = ((long long)blockIdx.y * T + t) * (long long)T;
    const unsigned short* srow = S + base;
    unsigned short* prow = P + base;
    const int n = t + 1;                       // valid causal length
    const int lim = ((t >> 7) + 1) << 7;       // zero-fill to 128 boundary
    const int tid = threadIdx.x;

    const int n8 = n >> 3;
    for (int i = tid; i < n8; i += 256) {
        int4 r = ((const int4*)srow)[i];
        const unsigned short* u = (const unsigned short*)&r;
#pragma unroll
        for (int j = 0; j < 8; ++j) rowl[i * 8 + j] = bf2f(u[j]);
    }
    for (int i = (n8 << 3) + tid; i < n; i += 256) rowl[i] = bf2f(srow[i]);
    __syncthreads();

    float mx = -3.0e38f;
    for (int i = tid; i < n; i += 256) mx = fmaxf(mx, rowl[i]);
#pragma unroll
    for (int off = 32; off > 0; off >>= 1) mx = fmaxf(mx, __shfl_xor(mx, off));
    if ((tid & 63) == 0) sred[tid >> 6] = mx;
    __syncthreads();
    mx = fmaxf(fmaxf(sred[0], sred[1]), fmaxf(sred[2], sred[3]));
    __syncthreads();

    float sum = 0.f;
    for (int i = tid; i < n; i += 256) {
        float e = __expf(rowl[i] - mx);
        rowl[i] = e;
        sum += e;
    }
#pragma unroll
    for (int off = 32; off > 0; off >>= 1) sum += __shfl_xor(sum, off);
    if ((tid & 63) == 0) sred[tid >> 6] = sum;
    __syncthreads();
    sum = sred[0] + sred[1] + sred[2] + sred[3];
    const float inv = 1.0f / sum;

    for (int i = tid; i < n; i += 256) prow[i] = f2bf(rowl[i] * inv);
    for (int i = n + tid; i < lim; i += 256) prow[i] = 0;
}

// ---------------------------------------------------------------------------
extern "C" void kernel_launch(void* const* d_in, const int* in_sizes, int n_in,
                              void* d_out, int out_size, void* d_ws, size_t ws_size,
                              hipStream_t stream)
{
    const int B = 4, T = 2048, C = 1024, F = 4096;
    const float* x   = (const float*)d_in[0];
    const float* Wk  = (const float*)d_in[1];
    const float* Wq  = (const float*)d_in[2];
    const float* Wv  = (const float*)d_in[3];
    const float* W1  = (const float*)d_in[4];
    const float* b1  = (const float*)d_in[5];
    const float* W2  = (const float*)d_in[6];
    const float* b2  = (const float*)d_in[7];
    const float* g1  = (const float*)d_in[8];
    const float* be1 = (const float*)d_in[9];
    const float* g2  = (const float*)d_in[10];
    const float* be2 = (const float*)d_in[11];

    char* ws = (char*)d_ws;
    const size_t MB = 1ull << 20;
    unsigned short* h     = (unsigned short*)(ws + 0);         // 16 MiB
    unsigned short* qkv   = (unsigned short*)(ws + 16 * MB);   // 48 MiB [8192][3072]
    unsigned short* vT    = (unsigned short*)(ws + 64 * MB);   // 16 MiB [1024][8192]
    float*          xres  = (float*)(ws + 80 * MB);            // 32 MiB
    unsigned short* S     = (unsigned short*)(ws + 112 * MB);  // 32 MiB bf16 [B][T][T]
    unsigned short* P     = (unsigned short*)(ws + 144 * MB);  // 32 MiB
    unsigned short* ff1   = (unsigned short*)(ws + 112 * MB);  // 64 MiB (aliases S+P; used after pv)
    unsigned short* wqkvT = (unsigned short*)(ws + 176 * MB);  // 6 MiB [3C][C]
    unsigned short* w1T   = (unsigned short*)(ws + 182 * MB);  // 8 MiB [F][C]
    unsigned short* w2T   = (unsigned short*)(ws + 190 * MB);  // 8 MiB [C][F]  (end 198 MiB)

    // transposed weight converts (q,k,v fused into wqkvT)
    tconv_k<<<dim3(16, 16), 256, 0, stream>>>(Wq, wqkvT, C, C);
    tconv_k<<<dim3(16, 16), 256, 0, stream>>>(Wk, wqkvT + C * C, C, C);
    tconv_k<<<dim3(16, 16), 256, 0, stream>>>(Wv, wqkvT + 2 * C * C, C, C);
    tconv_k<<<dim3(64, 16), 256, 0, stream>>>(W1, w1T, C, F);
    tconv_k<<<dim3(16, 64), 256, 0, stream>>>(W2, w2T, F, C);

    // LN1
    ln_k<<<dim3(B * T / 4), 256, 0, stream>>>(x, g1, be1, h);

    // [q|k|v] = h @ [Wq|Wk|Wv]   (M=8192, N=3072, K=1024) -> 1536 blocks
    dim3 gqkv(3 * C / 128, (B * T) / 128, 1);
    gemm128<EPI_BF16, false, false><<<gqkv, 256, 0, stream>>>(
        h, wqkvT, qkv, nullptr, nullptr, B * T, 3 * C, C, C, C, 1.0f, 0, 0, 0, 0);

    // vT = transpose of v-slice
    vtrans_k<<<dim3(B * T / 64, C / 64), 256, 0, stream>>>(qkv, vT);

    // S = q @ k^T / 32 (bf16 out; causal tiles only) -> 544 alive
    dim3 gsc(T / 128, T / 128, B);
    gemm128<EPI_BF16, true, false><<<gsc, 256, 0, stream>>>(
        qkv, qkv + C, S, nullptr, nullptr, T, T, C, 3 * C, 3 * C, 0.03125f,
        (long long)T * 3 * C, (long long)T * 3 * C, (long long)T * T, 0);

    // P = causal softmax(S)
    softmax_k<<<dim3(T, B), 256, 0, stream>>>(S, P, T);

    // xres = x + P @ v  (B = vT [C][8192], batch col-offset T) -> 512 blocks
    dim3 gsa(C / 128, T / 128, B);
    gemm128<EPI_RESID_F32, false, true><<<gsa, 256, 0, stream>>>(
        P, vT, xres, nullptr, x, T, C, T, T, B * T, 1.0f,
        (long long)T * T, (long long)T, (long long)T * C, (long long)T * C);

    // LN2
    ln_k<<<dim3(B * T / 4), 256, 0, stream>>>(xres, g2, be2, h);

    // ff1 = relu(h @ W1 + b1)   (M=8192, N=4096, K=1024) -> 2048 blocks
    dim3 gf1(F / 128, (B * T) / 128, 1);
    gemm128<EPI_BIAS_RELU_BF16, false, false><<<gf1, 256, 0, stream>>>(
        h, w1T, ff1, b1, nullptr, B * T, F, C, C, C, 1.0f, 0, 0, 0, 0);

    // out = xres + ff1 @ W2 + b2   (M=8192, N=1024, K=4096) -> 512 blocks
    dim3 gf2(C / 128, (B * T) / 128, 1);
    gemm128<EPI_BIAS_RESID_F32, false, false><<<gf2, 256, 0, stream>>>(
        ff1, w2T, (float*)d_out, b2, xres, B * T, C, F, F, F, 1.0f, 0, 0, 0, 0);
}

// Round 11
// 371.754 us; speedup vs baseline: 1.0941x; 1.0248x over previous
//
#include <hip/hip_runtime.h>
#include <hip/hip_bf16.h>

// ---------------------------------------------------------------------------
// Transformer block forward (B=4, T=2048, C=1024, F=4096).
// TWO GEMM engines, selected per op by measured perf:
//  - gemm256: 256x256 tile, 512 thr, 8 waves 2Mx4N, 4 phases/K-tile with
//    alternating acc quadrants, counted vmcnt (r9: 897 TF @ff1).  Used for
//    qkv / scores / ff1 (grids that fill with 256 tiles).
//  - gemm128: 128x128 tile, 256 thr, 4 waves, 64 KiB LDS -> 2 blocks/CU
//    (r10).  Used for pv (KLIM) and ff2 (direct bias+resid epilogue).
// Both: T2 (row>>1)&3 swizzle (bank-conflict 0, verified r8-r10), T5
// setprio, T1 bijective XCD swizzle, global_load_lds width-16 staging.
// ---------------------------------------------------------------------------

typedef __bf16 bf16x8_t __attribute__((ext_vector_type(8)));
typedef float f32x4_t __attribute__((ext_vector_type(4)));

__device__ __forceinline__ unsigned short f2bf(float f) {
    unsigned int u = __float_as_uint(f);
    u += 0x7fffu + ((u >> 16) & 1u);   // round-to-nearest-even
    return (unsigned short)(u >> 16);
}
__device__ __forceinline__ float bf2f(unsigned short u) {
    return __uint_as_float((unsigned int)u << 16);
}

__device__ __forceinline__ void gload16(const void* g, void* lds) {
    __builtin_amdgcn_global_load_lds(
        (const __attribute__((address_space(1))) unsigned int*)g,
        (__attribute__((address_space(3))) unsigned int*)lds, 16, 0, 0);
}

#define SB0() __builtin_amdgcn_sched_barrier(0)
#define BAR_LGKM() asm volatile("s_barrier\ns_waitcnt lgkmcnt(0)" ::: "memory")
#define BAR() asm volatile("s_barrier" ::: "memory")
#define VM4_BAR() asm volatile("s_waitcnt vmcnt(4)\ns_barrier" ::: "memory")
#define VM0_BAR() asm volatile("s_waitcnt vmcnt(0)\ns_barrier" ::: "memory")

enum { EPI_F32 = 0, EPI_BF16 = 1, EPI_BIAS_RELU_BF16 = 2, EPI_RESID_F32 = 3,
       EPI_BIAS_RESID_F32 = 4 };

// ======================= 256x256 engine (r9) ===============================
// LDS: buf*65536 + kk*32768 + op*16384; region 256 rows x 32 k bf16;
// chunk c=row*4+s at byte c*16; slot s holds global k-slot s^((row>>1)&3).
template <int EPI, bool CSKIP, bool KLIM>
__global__ __launch_bounds__(512, 2) void gemm256(
    const unsigned short* __restrict__ A,
    const unsigned short* __restrict__ Bm,
    void* __restrict__ Cout,
    const float* __restrict__ bias,
    const float* __restrict__ resid,
    int M, int N, int K, int lda, int ldb, float scale,
    long long batA, long long batB, long long batC, long long batR)
{
    __shared__ __align__(16) unsigned char lds[131072];

    const int gx = gridDim.x;
    const int nwg = gx * gridDim.y;
    int bl = blockIdx.y * gx + blockIdx.x;
    bl = (bl & 7) * (nwg >> 3) + (bl >> 3);
    const int bx = bl % gx, by = bl / gx;

    const int row0 = by * 256, col0 = bx * 256;
    if (CSKIP && col0 > row0) return;

    const int bz = blockIdx.z;
    const unsigned short* Ab = A + (long long)bz * batA + (long long)row0 * lda;
    const unsigned short* Bb = Bm + (long long)bz * batB + (long long)col0 * ldb;

    const int tid = threadIdx.x, lane = tid & 63, wid = tid >> 6;
    const int wrM = (wid >> 2) * 128;
    const int wcN = (wid & 3) * 64;
    const int lr = lane & 15, lg = lane >> 4;

    int Keff = K;
    if (KLIM) { int kl = row0 + 256; Keff = kl < K ? kl : K; }
    const int nkt = Keff >> 6;

    const int c0 = wid * 128 + lane;
    const int crow = c0 >> 2;
    const int sg = (c0 & 3) ^ ((c0 >> 3) & 3);
    const unsigned short* gA0 = Ab + (long long)crow * lda + sg * 8;
    const unsigned short* gA1 = gA0 + 16ll * lda;
    const unsigned short* gB0 = Bb + (long long)crow * ldb + sg * 8;
    const unsigned short* gB1 = gB0 + 16ll * ldb;

    const int sw = (lg ^ ((lr >> 1) & 3)) << 4;
    const int aoff = (wrM + lr) * 64 + sw;
    const int boff = 16384 + (wcN + lr) * 64 + sw;

    f32x4_t acc[8][4];
#pragma unroll
    for (int m = 0; m < 8; ++m)
#pragma unroll
        for (int n = 0; n < 4; ++n)
            acc[m][n] = (f32x4_t){0.f, 0.f, 0.f, 0.f};

    auto stageR = [&](int b, int r, int ktn) {
        const int kk = r >> 1, op = r & 1;
        const int ke = ktn * 64 + kk * 32;
        unsigned char* d = lds + b * 65536 + kk * 32768 + op * 16384 + wid * 2048;
        const unsigned short* g0 = (op ? gB0 : gA0) + ke;
        const unsigned short* g1 = (op ? gB1 : gA1) + ke;
        gload16(g0, d);
        gload16(g1, d + 1024);
    };

    bf16x8_t af[4], bv[4];
    auto dsA4 = [&](int b, int kk, int mq) {
        const unsigned char* u = lds + b * 65536 + kk * 32768;
#pragma unroll
        for (int j = 0; j < 4; ++j)
            af[j] = *(const bf16x8_t*)(u + aoff + (mq * 4 + j) * 1024);
    };
    auto dsB4 = [&](int b, int kk) {
        const unsigned char* u = lds + b * 65536 + kk * 32768;
#pragma unroll
        for (int n = 0; n < 4; ++n)
            bv[n] = *(const bf16x8_t*)(u + boff + n * 1024);
    };
    auto mf16 = [&](int mq) {
        __builtin_amdgcn_s_setprio(1);
#pragma unroll
        for (int j = 0; j < 4; ++j)
#pragma unroll
            for (int n = 0; n < 4; ++n)
                acc[mq * 4 + j][n] = __builtin_amdgcn_mfma_f32_16x16x32_bf16(
                    af[j], bv[n], acc[mq * 4 + j][n], 0, 0, 0);
        __builtin_amdgcn_s_setprio(0);
    };

    stageR(0, 0, 0); stageR(0, 1, 0); stageR(0, 2, 0); stageR(0, 3, 0);
    VM4_BAR();

    int kt = 0;
    for (; kt < nkt - 1; ++kt) {
        const int buf = kt & 1, nb = buf ^ 1;
        dsA4(buf, 0, 0); dsB4(buf, 0);
        stageR(nb, 0, kt + 1);
        BAR_LGKM(); SB0();
        mf16(0); SB0();
        BAR();
        dsA4(buf, 0, 1);
        stageR(nb, 1, kt + 1);
        BAR_LGKM(); SB0();
        mf16(1); SB0();
        VM4_BAR();
        dsA4(buf, 1, 0); dsB4(buf, 1);
        stageR(nb, 2, kt + 1);
        BAR_LGKM(); SB0();
        mf16(0); SB0();
        BAR();
        dsA4(buf, 1, 1);
        stageR(nb, 3, kt + 1);
        BAR_LGKM(); SB0();
        mf16(1); SB0();
        VM4_BAR();
    }
    {
        const int buf = kt & 1;
        dsA4(buf, 0, 0); dsB4(buf, 0);
        BAR_LGKM(); SB0();
        mf16(0); SB0();
        BAR();
        dsA4(buf, 0, 1);
        BAR_LGKM(); SB0();
        mf16(1); SB0();
        VM0_BAR();
        dsA4(buf, 1, 0); dsB4(buf, 1);
        BAR_LGKM(); SB0();
        mf16(0); SB0();
        BAR();
        dsA4(buf, 1, 1);
        BAR_LGKM(); SB0();
        mf16(1); SB0();
    }

    const int ldc = N;
    float* Cf = (float*)Cout + (long long)bz * batC;
    unsigned short* Cb = (unsigned short*)Cout + (long long)bz * batC;
    const float* R = nullptr;
    if constexpr (EPI == EPI_RESID_F32 || EPI == EPI_BIAS_RESID_F32)
        R = resid + (long long)bz * batR;

#pragma unroll
    for (int m = 0; m < 8; ++m)
#pragma unroll
        for (int n = 0; n < 4; ++n)
#pragma unroll
            for (int j = 0; j < 4; ++j) {
                const int row = row0 + wrM + m * 16 + lg * 4 + j;
                const int col = col0 + wcN + n * 16 + lr;
                const long long idx = (long long)row * ldc + col;
                float v = acc[m][n][j] * scale;
                if constexpr (EPI == EPI_F32) {
                    Cf[idx] = v;
                } else if constexpr (EPI == EPI_BF16) {
                    Cb[idx] = f2bf(v);
                } else if constexpr (EPI == EPI_BIAS_RELU_BF16) {
                    v += bias[col];
                    v = v > 0.f ? v : 0.f;
                    Cb[idx] = f2bf(v);
                } else if constexpr (EPI == EPI_RESID_F32) {
                    Cf[idx] = v + R[idx];
                } else {
                    Cf[idx] = v + bias[col] + R[idx];
                }
            }
}

// ======================= 128x128 engine (r10) ==============================
// LDS: buf*32768 + kk*16384 + op*8192; region 128 rows x 32 k bf16.
template <int EPI, bool CSKIP, bool KLIM>
__global__ __launch_bounds__(256, 2) void gemm128(
    const unsigned short* __restrict__ A,
    const unsigned short* __restrict__ Bm,
    void* __restrict__ Cout,
    const float* __restrict__ bias,
    const float* __restrict__ resid,
    int M, int N, int K, int lda, int ldb, float scale,
    long long batA, long long batB, long long batC, long long batR)
{
    __shared__ __align__(16) unsigned char lds[65536];

    const int gx = gridDim.x;
    const int nwg = gx * gridDim.y;
    int bl = blockIdx.y * gx + blockIdx.x;
    bl = (bl & 7) * (nwg >> 3) + (bl >> 3);
    const int bx = bl % gx, by = bl / gx;

    const int row0 = by * 128, col0 = bx * 128;
    if (CSKIP && col0 > row0) return;

    const int bz = blockIdx.z;
    const unsigned short* Ab = A + (long long)bz * batA + (long long)row0 * lda;
    const unsigned short* Bb = Bm + (long long)bz * batB + (long long)col0 * ldb;

    const int tid = threadIdx.x, lane = tid & 63, wid = tid >> 6;
    const int wrM = (wid >> 1) * 64;
    const int wcN = (wid & 1) * 64;
    const int lr = lane & 15, lg = lane >> 4;

    int Keff = K;
    if (KLIM) { int kl = row0 + 128; Keff = kl < K ? kl : K; }
    const int nkt = Keff >> 6;

    const int c0 = wid * 128 + lane;
    const int crow = c0 >> 2;
    const int sg = (c0 & 3) ^ ((c0 >> 3) & 3);
    const unsigned short* gA0 = Ab + (long long)crow * lda + sg * 8;
    const unsigned short* gA1 = gA0 + 16ll * lda;
    const unsigned short* gB0 = Bb + (long long)crow * ldb + sg * 8;
    const unsigned short* gB1 = gB0 + 16ll * ldb;

    const int sw = (lg ^ ((lr >> 1) & 3)) << 4;
    const int aoff = (wrM + lr) * 64 + sw;
    const int boff = 8192 + (wcN + lr) * 64 + sw;

    f32x4_t acc[4][4];
#pragma unroll
    for (int m = 0; m < 4; ++m)
#pragma unroll
        for (int n = 0; n < 4; ++n)
            acc[m][n] = (f32x4_t){0.f, 0.f, 0.f, 0.f};

    auto stage2 = [&](int b, int kk, int ktn) {
        const int ke = ktn * 64 + kk * 32;
        unsigned char* uA = lds + b * 32768 + kk * 16384 + wid * 2048;
        unsigned char* uB = uA + 8192;
        gload16(gA0 + ke, uA);
        gload16(gA1 + ke, uA + 1024);
        gload16(gB0 + ke, uB);
        gload16(gB1 + ke, uB + 1024);
    };

    bf16x8_t af[4], bv[4];
    auto dsAB = [&](int b, int kk) {
        const unsigned char* u = lds + b * 32768 + kk * 16384;
#pragma unroll
        for (int m = 0; m < 4; ++m)
            af[m] = *(const bf16x8_t*)(u + aoff + m * 1024);
#pragma unroll
        for (int n = 0; n < 4; ++n)
            bv[n] = *(const bf16x8_t*)(u + boff + n * 1024);
    };
    auto mf16 = [&]() {
        __builtin_amdgcn_s_setprio(1);
#pragma unroll
        for (int m = 0; m < 4; ++m)
#pragma unroll
            for (int n = 0; n < 4; ++n)
                acc[m][n] = __builtin_amdgcn_mfma_f32_16x16x32_bf16(
                    af[m], bv[n], acc[m][n], 0, 0, 0);
        __builtin_amdgcn_s_setprio(0);
    };

    stage2(0, 0, 0); stage2(0, 1, 0);
    VM4_BAR();

    int kt = 0;
    for (; kt < nkt - 1; ++kt) {
        const int buf = kt & 1, nb = buf ^ 1;
        dsAB(buf, 0);
        stage2(nb, 0, kt + 1);
        BAR_LGKM(); SB0();
        mf16(); SB0();
        VM4_BAR();
        dsAB(buf, 1);
        stage2(nb, 1, kt + 1);
        BAR_LGKM(); SB0();
        mf16(); SB0();
        VM4_BAR();
    }
    {
        const int buf = kt & 1;
        dsAB(buf, 0);
        BAR_LGKM(); SB0();
        mf16(); SB0();
        VM0_BAR();
        dsAB(buf, 1);
        BAR_LGKM(); SB0();
        mf16(); SB0();
    }

    const int ldc = N;
    float* Cf = (float*)Cout + (long long)bz * batC;
    unsigned short* Cb = (unsigned short*)Cout + (long long)bz * batC;
    const float* R = nullptr;
    if constexpr (EPI == EPI_RESID_F32 || EPI == EPI_BIAS_RESID_F32)
        R = resid + (long long)bz * batR;

#pragma unroll
    for (int m = 0; m < 4; ++m)
#pragma unroll
        for (int n = 0; n < 4; ++n)
#pragma unroll
            for (int j = 0; j < 4; ++j) {
                const int row = row0 + wrM + m * 16 + lg * 4 + j;
                const int col = col0 + wcN + n * 16 + lr;
                const long long idx = (long long)row * ldc + col;
                float v = acc[m][n][j] * scale;
                if constexpr (EPI == EPI_F32) {
                    Cf[idx] = v;
                } else if constexpr (EPI == EPI_BF16) {
                    Cb[idx] = f2bf(v);
                } else if constexpr (EPI == EPI_BIAS_RELU_BF16) {
                    v += bias[col];
                    v = v > 0.f ? v : 0.f;
                    Cb[idx] = f2bf(v);
                } else if constexpr (EPI == EPI_RESID_F32) {
                    Cf[idx] = v + R[idx];
                } else {
                    Cf[idx] = v + bias[col] + R[idx];
                }
            }
}

// ------------- transpose + fp32->bf16 convert: in [R][Cc] -> out [Cc][R] ----
__global__ __launch_bounds__(256) void tconv_k(
    const float* __restrict__ in, unsigned short* __restrict__ out,
    int R, int Cc)
{
    __shared__ float t[64][65];
    const int r0 = blockIdx.y * 64, c0 = blockIdx.x * 64;
    const int tid = threadIdx.x;
    const int a = tid >> 4;
    const int b = tid & 15;
#pragma unroll
    for (int i = 0; i < 4; ++i) {
        const int row = a + i * 16;
        float4 v = *(const float4*)(in + (long long)(r0 + row) * Cc + c0 + b * 4);
        t[row][b * 4 + 0] = v.x; t[row][b * 4 + 1] = v.y;
        t[row][b * 4 + 2] = v.z; t[row][b * 4 + 3] = v.w;
    }
    __syncthreads();
#pragma unroll
    for (int i = 0; i < 4; ++i) {
        const int oc = a + i * 16;
        ushort4 o;
        o.x = f2bf(t[b * 4 + 0][oc]);
        o.y = f2bf(t[b * 4 + 1][oc]);
        o.z = f2bf(t[b * 4 + 2][oc]);
        o.w = f2bf(t[b * 4 + 3][oc]);
        *(ushort4*)(out + (long long)(c0 + oc) * R + r0 + b * 4) = o;
    }
}

// ------ bf16 transpose of the v-slice: qkv[8192][3072]@col2048 -> vT[1024][8192]
__global__ __launch_bounds__(256) void vtrans_k(
    const unsigned short* __restrict__ in, unsigned short* __restrict__ out)
{
    __shared__ unsigned short t[64][72];
    const int r0 = blockIdx.x * 64;
    const int c0 = blockIdx.y * 64;
    const int tid = threadIdx.x;
#pragma unroll
    for (int i = 0; i < 2; ++i) {
        const int ch = tid * 2 + i;
        const int row = ch >> 3, cs = ch & 7;
        int4 v = *(const int4*)(in + (long long)(r0 + row) * 3072 + 2048 + c0 + cs * 8);
        *(int4*)&t[row][cs * 8] = v;
    }
    __syncthreads();
#pragma unroll
    for (int i = 0; i < 2; ++i) {
        const int w = tid * 2 + i;
        const int oc = w >> 3, orc = w & 7;
        unsigned short tmp[8];
#pragma unroll
        for (int j = 0; j < 8; ++j) tmp[j] = t[orc * 8 + j][oc];
        *(int4*)(out + (long long)(c0 + oc) * 8192 + r0 + orc * 8) = *(const int4*)tmp;
    }
}

// ---------------- LayerNorm: one wave per 1024-elem row ---------------------
__global__ __launch_bounds__(256) void ln_k(
    const float* __restrict__ x, const float* __restrict__ g,
    const float* __restrict__ be, unsigned short* __restrict__ out)
{
    const int wv = threadIdx.x >> 6, lane = threadIdx.x & 63;
    const long long row = blockIdx.x * 4 + wv;
    const float* xr = x + row * 1024;
    float4 v[4];
    float s = 0.f, q = 0.f;
#pragma unroll
    for (int j = 0; j < 4; ++j) {
        v[j] = *(const float4*)(xr + j * 256 + lane * 4);
        s += v[j].x + v[j].y + v[j].z + v[j].w;
        q += v[j].x * v[j].x + v[j].y * v[j].y + v[j].z * v[j].z + v[j].w * v[j].w;
    }
#pragma unroll
    for (int off = 32; off > 0; off >>= 1) {
        s += __shfl_xor(s, off);
        q += __shfl_xor(q, off);
    }
    const float mean = s * (1.0f / 1024.0f);
    const float var  = q * (1.0f / 1024.0f) - mean * mean;
    const float rstd = rsqrtf(var + 1e-5f);
#pragma unroll
    for (int j = 0; j < 4; ++j) {
        float4 gv = *(const float4*)(g + j * 256 + lane * 4);
        float4 bv = *(const float4*)(be + j * 256 + lane * 4);
        ushort4 o;
        o.x = f2bf((v[j].x - mean) * rstd * gv.x + bv.x);
        o.y = f2bf((v[j].y - mean) * rstd * gv.y + bv.y);
        o.z = f2bf((v[j].z - mean) * rstd * gv.z + bv.z);
        o.w = f2bf((v[j].w - mean) * rstd * gv.w + bv.w);
        *(ushort4*)(out + row * 1024 + j * 256 + lane * 4) = o;
    }
}

// ------------- causal row softmax: S bf16 -> P bf16 (zero-padded) ----------
__global__ __launch_bounds__(256) void softmax_k(
    const unsigned short* __restrict__ S, unsigned short* __restrict__ P, int T)
{
    __shared__ float rowl[2048];
    __shared__ float sred[4];
    const int t = blockIdx.x;
    const long long base = ((long long)blockIdx.y * T + t) * (long long)T;
    const unsigned short* srow = S + base;
    unsigned short* prow = P + base;
    const int n = t + 1;                       // valid causal length
    const int lim = ((t >> 7) + 1) << 7;       // zero-fill to 128 boundary
    const int tid = threadIdx.x;

    const int n8 = n >> 3;
    for (int i = tid; i < n8; i += 256) {
        int4 r = ((const int4*)srow)[i];
        const unsigned short* u = (const unsigned short*)&r;
#pragma unroll
        for (int j = 0; j < 8; ++j) rowl[i * 8 + j] = bf2f(u[j]);
    }
    for (int i = (n8 << 3) + tid; i < n; i += 256) rowl[i] = bf2f(srow[i]);
    __syncthreads();

    float mx = -3.0e38f;
    for (int i = tid; i < n; i += 256) mx = fmaxf(mx, rowl[i]);
#pragma unroll
    for (int off = 32; off > 0; off >>= 1) mx = fmaxf(mx, __shfl_xor(mx, off));
    if ((tid & 63) == 0) sred[tid >> 6] = mx;
    __syncthreads();
    mx = fmaxf(fmaxf(sred[0], sred[1]), fmaxf(sred[2], sred[3]));
    __syncthreads();

    float sum = 0.f;
    for (int i = tid; i < n; i += 256) {
        float e = __expf(rowl[i] - mx);
        rowl[i] = e;
        sum += e;
    }
#pragma unroll
    for (int off = 32; off > 0; off >>= 1) sum += __shfl_xor(sum, off);
    if ((tid & 63) == 0) sred[tid >> 6] = sum;
    __syncthreads();
    sum = sred[0] + sred[1] + sred[2] + sred[3];
    const float inv = 1.0f / sum;

    for (int i = tid; i < n; i += 256) prow[i] = f2bf(rowl[i] * inv);
    for (int i = n + tid; i < lim; i += 256) prow[i] = 0;
}

// ---------------------------------------------------------------------------
extern "C" void kernel_launch(void* const* d_in, const int* in_sizes, int n_in,
                              void* d_out, int out_size, void* d_ws, size_t ws_size,
                              hipStream_t stream)
{
    const int B = 4, T = 2048, C = 1024, F = 4096;
    const float* x   = (const float*)d_in[0];
    const float* Wk  = (const float*)d_in[1];
    const float* Wq  = (const float*)d_in[2];
    const float* Wv  = (const float*)d_in[3];
    const float* W1  = (const float*)d_in[4];
    const float* b1  = (const float*)d_in[5];
    const float* W2  = (const float*)d_in[6];
    const float* b2  = (const float*)d_in[7];
    const float* g1  = (const float*)d_in[8];
    const float* be1 = (const float*)d_in[9];
    const float* g2  = (const float*)d_in[10];
    const float* be2 = (const float*)d_in[11];

    char* ws = (char*)d_ws;
    const size_t MB = 1ull << 20;
    unsigned short* h     = (unsigned short*)(ws + 0);         // 16 MiB
    unsigned short* qkv   = (unsigned short*)(ws + 16 * MB);   // 48 MiB [8192][3072]
    unsigned short* vT    = (unsigned short*)(ws + 64 * MB);   // 16 MiB [1024][8192]
    float*          xres  = (float*)(ws + 80 * MB);            // 32 MiB
    unsigned short* S     = (unsigned short*)(ws + 112 * MB);  // 32 MiB bf16 [B][T][T]
    unsigned short* P     = (unsigned short*)(ws + 144 * MB);  // 32 MiB
    unsigned short* ff1   = (unsigned short*)(ws + 112 * MB);  // 64 MiB (aliases S+P)
    unsigned short* wqkvT = (unsigned short*)(ws + 176 * MB);  // 6 MiB [3C][C]
    unsigned short* w1T   = (unsigned short*)(ws + 182 * MB);  // 8 MiB [F][C]
    unsigned short* w2T   = (unsigned short*)(ws + 190 * MB);  // 8 MiB [C][F]

    // transposed weight converts (q,k,v fused into wqkvT)
    tconv_k<<<dim3(16, 16), 256, 0, stream>>>(Wq, wqkvT, C, C);
    tconv_k<<<dim3(16, 16), 256, 0, stream>>>(Wk, wqkvT + C * C, C, C);
    tconv_k<<<dim3(16, 16), 256, 0, stream>>>(Wv, wqkvT + 2 * C * C, C, C);
    tconv_k<<<dim3(64, 16), 256, 0, stream>>>(W1, w1T, C, F);
    tconv_k<<<dim3(16, 64), 256, 0, stream>>>(W2, w2T, F, C);

    // LN1
    ln_k<<<dim3(B * T / 4), 256, 0, stream>>>(x, g1, be1, h);

    // [q|k|v] = h @ [Wq|Wk|Wv]   (M=8192, N=3072, K=1024) -> 384 blocks @256²
    dim3 gqkv(3 * C / 256, (B * T) / 256, 1);
    gemm256<EPI_BF16, false, false><<<gqkv, 512, 0, stream>>>(
        h, wqkvT, qkv, nullptr, nullptr, B * T, 3 * C, C, C, C, 1.0f, 0, 0, 0, 0);

    // vT = transpose of v-slice
    vtrans_k<<<dim3(B * T / 64, C / 64), 256, 0, stream>>>(qkv, vT);

    // S = q @ k^T / 32 (bf16 out; causal tiles only) -> 144 alive @256²
    dim3 gsc(T / 256, T / 256, B);
    gemm256<EPI_BF16, true, false><<<gsc, 512, 0, stream>>>(
        qkv, qkv + C, S, nullptr, nullptr, T, T, C, 3 * C, 3 * C, 0.03125f,
        (long long)T * 3 * C, (long long)T * 3 * C, (long long)T * T, 0);

    // P = causal softmax(S)
    softmax_k<<<dim3(T, B), 256, 0, stream>>>(S, P, T);

    // xres = x + P @ v  -> 512 blocks @128² (KLIM +128)
    dim3 gsa(C / 128, T / 128, B);
    gemm128<EPI_RESID_F32, false, true><<<gsa, 256, 0, stream>>>(
        P, vT, xres, nullptr, x, T, C, T, T, B * T, 1.0f,
        (long long)T * T, (long long)T, (long long)T * C, (long long)T * C);

    // LN2
    ln_k<<<dim3(B * T / 4), 256, 0, stream>>>(xres, g2, be2, h);

    // ff1 = relu(h @ W1 + b1)   (M=8192, N=4096, K=1024) -> 512 blocks @256²
    dim3 gf1(F / 256, (B * T) / 256, 1);
    gemm256<EPI_BIAS_RELU_BF16, false, false><<<gf1, 512, 0, stream>>>(
        h, w1T, ff1, b1, nullptr, B * T, F, C, C, C, 1.0f, 0, 0, 0, 0);

    // out = xres + ff1 @ W2 + b2   (M=8192, N=1024, K=4096) -> 512 blocks @128²
    dim3 gf2(C / 128, (B * T) / 128, 1);
    gemm128<EPI_BIAS_RESID_F32, false, false><<<gf2, 256, 0, stream>>>(
        ff1, w2T, (float*)d_out, b2, xres, B * T, C, F, F, F, 1.0f, 0, 0, 0, 0);
}